// Round 12
// baseline (411.354 us; speedup 1.0000x reference)
//
#include <hip/hip_runtime.h>

#define HH 256

typedef __attribute__((ext_vector_type(8))) short short8;
typedef __attribute__((ext_vector_type(4))) float f32x4;
typedef __attribute__((ext_vector_type(4))) unsigned short u16x4;
typedef __attribute__((ext_vector_type(8))) unsigned short u16x8;

constexpr int NBATCH = 16;
constexpr int T0   = 4096;
constexpr int FDIM = 1024;
constexpr int R0   = NBATCH * T0;   // 65536
constexpr int R1   = R0 / 2;        // 32768
constexpr int R2   = R0 / 4;        // 16384
constexpr int R3   = R0 / 8;        // 8192

__device__ __forceinline__ float b2f(unsigned short u) {
    union { unsigned int i; float f; } v; v.i = ((unsigned int)u) << 16; return v.f;
}
__device__ __forceinline__ unsigned short f2b(float f) {
    union { float f; unsigned int i; } v; v.f = f;
    unsigned int r = v.i + 0x7fffu + ((v.i >> 16) & 1u);
    return (unsigned short)(r >> 16);
}
__device__ __forceinline__ void gload16(const void* g, void* l) {
    __builtin_amdgcn_global_load_lds((const __attribute__((address_space(1))) void*)g,
                                     (__attribute__((address_space(3))) void*)l, 16, 0, 0);
}
// raw barrier: drain LDS ops, then s_barrier (no vmcnt drain -- that's the point)
__device__ __forceinline__ void barrier_sync() {
    asm volatile("s_waitcnt lgkmcnt(0)\n\ts_barrier" ::: "memory");
}
// counted vmem wait; n folds to a constant under full unroll
__device__ __forceinline__ void wait_vm(int n) {
    switch (n) {
    case 2:  asm volatile("s_waitcnt vmcnt(2)"  ::: "memory"); break;
    case 3:  asm volatile("s_waitcnt vmcnt(3)"  ::: "memory"); break;
    case 4:  asm volatile("s_waitcnt vmcnt(4)"  ::: "memory"); break;
    case 5:  asm volatile("s_waitcnt vmcnt(5)"  ::: "memory"); break;
    case 6:  asm volatile("s_waitcnt vmcnt(6)"  ::: "memory"); break;
    default: asm volatile("s_waitcnt vmcnt(0)"  ::: "memory"); break;
    }
}
// LDS slot swizzle: slot s (16B granules) holds k-group ks = (s&3) ^ ((s>>3)&3) of row s>>2.
__device__ __forceinline__ int swz_ks(int chunk)        { return (chunk & 3) ^ ((chunk >> 3) & 3); }
__device__ __forceinline__ int frag_idx(int row, int g) { return (row * 4 + (g ^ ((row >> 1) & 3))) * 8; }

struct PVv { u16x8 v0, v1, v2, v3; };

// ---------------- weight transpose+convert (merged): fp32 [K][256] -> bf16 [256][K] --------------
__device__ __forceinline__ void transpose_tile(const float* __restrict__ src,
                                               unsigned short* __restrict__ dst,
                                               int K, int tilesPerMat, int bid, int tidx)
{
    int m = bid / tilesPerMat;
    int t = bid % tilesPerMat;
    int tr = t >> 3, tc = t & 7;
    const float* S = src + (size_t)m * K * HH;
    unsigned short* D = dst + (size_t)m * HH * K;
    __shared__ float tile[32][33];
    int x = tidx & 31, y = tidx >> 5;
#pragma unroll
    for (int i = y; i < 32; i += 8)
        tile[i][x] = S[(size_t)(tr * 32 + i) * HH + tc * 32 + x];
    __syncthreads();
#pragma unroll
    for (int i = y; i < 32; i += 8)
        D[(size_t)(tc * 32 + i) * K + tr * 32 + x] = f2b(tile[x][i]);
}

__global__ void transpose_all(const float* __restrict__ Wself, const float* __restrict__ Wnbr,
                              const float* __restrict__ Wp,
                              unsigned short* __restrict__ Ws_t, unsigned short* __restrict__ Wn_t,
                              unsigned short* __restrict__ Wp_t)
{
    int bid = blockIdx.x;
    if (bid < 768)       transpose_tile(Wself, Ws_t, HH,   64,  bid,        threadIdx.x);
    else if (bid < 1536) transpose_tile(Wnbr,  Wn_t, HH,   64,  bid - 768,  threadIdx.x);
    else                 transpose_tile(Wp,    Wp_t, FDIM, 256, bid - 1536, threadIdx.x);
}

// ================= unified conv GEMM, single-pv depth pipeline, 2 blocks/CU target ===============
// out = Aeff @ Bself [+ nbrmean(Aeff) @ Bnbr] + bias, then leaky (LNFUSE=0) or LN+leaky (LNFUSE=1).
// AMODE 0: Aeff=A[r]  1: A[2r] (fused downsample)  2: A[r]+upsample2(Cc)[r] (fused up+residual)
// OUT (LNFUSE=1 only) 0: bf16  1: bf16 + prev[2r] residual  2: fp32 final
// __launch_bounds__(512,4): force VGPR<=128 so 2 blocks/CU co-reside (LDS <=76KB allows it).
template<int BM, int AMODE, int NBR, int LNFUSE, int OUT>
__launch_bounds__(512, 4)
__global__ void conv_fused(const unsigned short* __restrict__ A,
                           const unsigned short* __restrict__ Cc,
                           const unsigned short* __restrict__ prev,
                           const unsigned short* __restrict__ Bself,
                           const unsigned short* __restrict__ Bnbr,
                           const float* __restrict__ bias,
                           const float* __restrict__ lng,
                           const float* __restrict__ lnb,
                           void* __restrict__ dstv,
                           int Tl, int Tc, int tlshift)
{
    constexpr int NT = NBR ? 16 : 8;
    constexpr int MF = (BM + 31) / 32;   // m-frags per wave (BM=32 -> 1)
    constexpr int WROWS = BM / 2;        // rows per wave-m half
    __shared__ unsigned short As[3][BM * 32];
    __shared__ unsigned short Bs[3][256 * 32];
    __shared__ float lnred[LNFUSE ? BM : 1][8];

    const int tid  = threadIdx.x;
    const int lane = tid & 63;
    const int w    = tid >> 6;
    const int wm   = w & 1, wn = w >> 1;
    const long row0 = (long)blockIdx.x * BM;

    const bool hasA   = (tid < BM * 4);       // threads that stage A
    const bool hasA_w = (w < (BM * 4) / 64);  // wave-uniform version (for vmcnt counts)
    const int arr = tid >> 2;                 // staging row
    const int akk = swz_ks(tid);
    const long gr = row0 + (hasA ? arr : 0);

    // ---- producer precompute ----
    float ca = 0.f, cb = 0.f; size_t rc0 = 0, rc1 = 0;
    if (AMODE == 2) {
        int t = (int)(gr & (long)(Tl - 1));
        long bq = gr >> tlshift;
        int k = t >> 1;
        rc0 = (size_t)bq * Tc + k;
        if (!(t & 1))        { ca = 1.0f; cb = 0.0f; rc1 = rc0; }
        else if (k < Tc - 1) { ca = 0.5f; cb = 0.5f; rc1 = rc0 + 1; }
        else                 { ca = 0.9f; cb = 0.1f; rc1 = rc0 - 1; }
    }
    float vinv = 1.f;
    float cf0 = 0.f, cf1 = 0.f, cf2 = 0.f, cf3 = 0.f;
    size_t nrow0 = 0, nrow1 = 0, nrow2 = 0, nrow3 = 0;
    if (NBR) {
        const int offs[4] = {-2, -1, 1, 2};
        int t = (int)(gr & (long)(Tl - 1));
        int cnt = 0;
        float cf[4]; size_t nr[4];
#pragma unroll
        for (int oi = 0; oi < 4; oi++) {
            int tn = t + offs[oi];
            bool v = (tn >= 0 && tn < Tl);
            cnt += v ? 1 : 0;
            int tcl = tn < 0 ? 0 : (tn > Tl - 1 ? Tl - 1 : tn);
            long r = gr - t + tcl;
            nr[oi] = (size_t)((AMODE == 1) ? 2 * r : r) * HH;
            cf[oi] = v ? 1.f : 0.f;
        }
        vinv = 1.f / (float)cnt;
        cf0 = cf[0]; cf1 = cf[1]; cf2 = cf[2]; cf3 = cf[3];
        nrow0 = nr[0]; nrow1 = nr[1]; nrow2 = nr[2]; nrow3 = nr[3];
    }

    f32x4 acc[MF][4] = {};
    PVv pv = {};   // SINGLE prefetch set (VGPR budget: keep <=128/lane)

    // gload-group size per step for THIS wave (counted vmcnt); reg-loads excluded
    auto NG = [&](int t) -> int {
        if (!hasA_w) return 2;
        const int seg = (NBR && t >= 8) ? 1 : 0;
        return (seg == 0 && AMODE <= 1) ? 3 : 2;
    };
    // gload_lds part of staging (B always; A when it is a direct copy)
    auto issueG = [&](int t) {
        const int seg = (NBR && t >= 8) ? 1 : 0;
        const int k0 = (t & 7) * 32;
        const int sl = t % 3;
        const unsigned short* __restrict__ Bm = seg ? Bnbr : Bself;
        gload16(Bm + (size_t)arr * HH + k0 + akk * 8,         &Bs[sl][tid * 8]);
        gload16(Bm + (size_t)(128 + arr) * HH + k0 + akk * 8, &Bs[sl][(tid + 512) * 8]);
        if (hasA && seg == 0 && AMODE <= 1) {
            if (AMODE == 0)
                gload16(A + (size_t)gr * HH + k0 + akk * 8, &As[sl][tid * 8]);
            else
                gload16(A + (size_t)(2 * gr) * HH + k0 + akk * 8, &As[sl][tid * 8]);
        }
    };
    // register-load part of staging (producer inputs)
    auto issueR = [&](int t) {
        if (!hasA) return;
        const int seg = (NBR && t >= 8) ? 1 : 0;
        const int k0 = (t & 7) * 32;
        if (seg == 0) {
            if (AMODE == 2) {
                pv.v0 = *(const u16x8*)(A + (size_t)gr * HH + k0 + akk * 8);
                pv.v1 = *(const u16x8*)(Cc + rc0 * HH + k0 + akk * 8);
                pv.v2 = *(const u16x8*)(Cc + rc1 * HH + k0 + akk * 8);
            }
        } else {
            pv.v0 = *(const u16x8*)(A + nrow0 + k0 + akk * 8);
            pv.v1 = *(const u16x8*)(A + nrow1 + k0 + akk * 8);
            pv.v2 = *(const u16x8*)(A + nrow2 + k0 + akk * 8);
            pv.v3 = *(const u16x8*)(A + nrow3 + k0 + akk * 8);
        }
    };
    auto finishA = [&](int t) {
        if (!hasA) return;
        const int seg = (NBR && t >= 8) ? 1 : 0;
        const int sl = t % 3;
        if (seg == 0) {
            if (AMODE == 2) {
                u16x8 o;
#pragma unroll
                for (int j = 0; j < 8; j++)
                    o[j] = f2b(b2f(pv.v0[j]) + ca * b2f(pv.v1[j]) + cb * b2f(pv.v2[j]));
                *(u16x8*)&As[sl][tid * 8] = o;
            }
        } else {
            u16x8 o;
#pragma unroll
            for (int j = 0; j < 8; j++) {
                float a = cf0 * b2f(pv.v0[j]) + cf1 * b2f(pv.v1[j])
                        + cf2 * b2f(pv.v2[j]) + cf3 * b2f(pv.v3[j]);
                o[j] = f2b(a * vinv);
            }
            *(u16x8*)&As[sl][tid * 8] = o;
        }
    };

    // ---- prologue ----
    issueG(0);
    issueR(0);
    issueG(1);
    wait_vm(NG(1));   // leaves only G(1) outstanding -> G(0)+R(0) complete
    finishA(0);
    issueR(1);
    barrier_sync();

#pragma unroll
    for (int t = 0; t < NT; ++t) {
        if (t + 2 < NT) issueG(t + 2);

        const int sl = t % 3;
        __builtin_amdgcn_s_setprio(1);
        short8 af[MF], bg[4];
#pragma unroll
        for (int i = 0; i < MF; i++)
            af[i] = *(const short8*)&As[sl][frag_idx(wm * WROWS + i * 16 + (lane & 15), lane >> 4)];
#pragma unroll
        for (int i = 0; i < 4; i++)
            bg[i] = *(const short8*)&Bs[sl][frag_idx(wn * 64 + i * 16 + (lane & 15), lane >> 4)];
#pragma unroll
        for (int mi = 0; mi < MF; mi++)
#pragma unroll
            for (int ni = 0; ni < 4; ni++)
                acc[mi][ni] = __builtin_amdgcn_mfma_f32_16x16x32_bf16(af[mi], bg[ni], acc[mi][ni], 0, 0, 0);
        __builtin_amdgcn_s_setprio(0);

        if (t + 1 < NT) {
            wait_vm((t + 2 < NT) ? NG(t + 2) : 0);   // R(t+1)+G(t+1) complete
            finishA(t + 1);
            if (t + 2 < NT) issueR(t + 2);           // reuse pv after finish consumed it
            barrier_sync();
        }
    }

    // ---- epilogue ----
    if (LNFUSE == 0) {
        unsigned short* outp = (unsigned short*)dstv;
#pragma unroll
        for (int mi = 0; mi < MF; mi++) {
            size_t rbase = (size_t)row0 + wm * WROWS + mi * 16 + (lane >> 4) * 4;
#pragma unroll
            for (int ni = 0; ni < 4; ni++) {
                int c = wn * 64 + ni * 16 + (lane & 15);
                float bb = bias[c];
                f32x4 v = acc[mi][ni];
#pragma unroll
                for (int r = 0; r < 4; r++) {
                    float t = v[r] + bb;
                    t = (t >= 0.f) ? t : 0.2f * t;
                    outp[(rbase + r) * HH + c] = f2b(t);
                }
            }
        }
    } else {
        float bb[4];
#pragma unroll
        for (int ni = 0; ni < 4; ni++) bb[ni] = bias[wn * 64 + ni * 16 + (lane & 15)];

#pragma unroll
        for (int mi = 0; mi < MF; mi++) {
#pragma unroll
            for (int r = 0; r < 4; r++) {
                float s = 0.f, q = 0.f;
#pragma unroll
                for (int ni = 0; ni < 4; ni++) {
                    float v = acc[mi][ni][r] + bb[ni];
                    s += v; q += v * v;
                }
                s += __shfl_xor(s, 1); q += __shfl_xor(q, 1);
                s += __shfl_xor(s, 2); q += __shfl_xor(q, 2);
                s += __shfl_xor(s, 4); q += __shfl_xor(q, 4);
                s += __shfl_xor(s, 8); q += __shfl_xor(q, 8);
                if ((lane & 15) == 0) {
                    int row = wm * WROWS + mi * 16 + (lane >> 4) * 4 + r;
                    lnred[row][wn]     = s;
                    lnred[row][4 + wn] = q;
                }
            }
        }
        __syncthreads();

        float gv[4], bv[4];
#pragma unroll
        for (int ni = 0; ni < 4; ni++) {
            int c = wn * 64 + ni * 16 + (lane & 15);
            gv[ni] = lng[c]; bv[ni] = lnb[c];
        }

#pragma unroll
        for (int mi = 0; mi < MF; mi++) {
#pragma unroll
            for (int r = 0; r < 4; r++) {
                int row = wm * WROWS + mi * 16 + (lane >> 4) * 4 + r;
                float s = lnred[row][0] + lnred[row][1] + lnred[row][2] + lnred[row][3];
                float q = lnred[row][4] + lnred[row][5] + lnred[row][6] + lnred[row][7];
                float mu  = s * (1.0f / HH);
                float var = q * (1.0f / HH) - mu * mu;
                float inv = rsqrtf(var + 1e-5f);
                size_t grow = (size_t)row0 + row;
#pragma unroll
                for (int ni = 0; ni < 4; ni++) {
                    int c = wn * 64 + ni * 16 + (lane & 15);
                    float v = acc[mi][ni][r] + bb[ni];
                    float y = (v - mu) * inv * gv[ni] + bv[ni];
                    y = (y >= 0.f) ? y : 0.2f * y;
                    if (OUT == 2) {
                        ((float*)dstv)[grow * HH + c] = y;
                    } else {
                        if (OUT == 1) y += b2f(prev[(2 * grow) * HH + c]);
                        ((unsigned short*)dstv)[grow * HH + c] = f2b(y);
                    }
                }
            }
        }
    }
}

// ---------------- projection GEMM, single-pa pipeline: A fp32 -> bf16 producer --------------------
__launch_bounds__(512, 4)
__global__ void proj_gemm(const float* __restrict__ A, const unsigned short* __restrict__ Bt,
                          const float* __restrict__ bias, unsigned short* __restrict__ out)
{
    constexpr int NT = FDIM / 32;   // 32
    __shared__ unsigned short As[3][128 * 32];
    __shared__ unsigned short Bs[3][256 * 32];
    const int tid  = threadIdx.x;
    const int lane = tid & 63;
    const int w    = tid >> 6;
    const int wm   = w & 1, wn = w >> 1;
    const size_t row0 = (size_t)blockIdx.x * 128;

    const int arr = tid >> 2;
    const int akk = swz_ks(tid);

    f32x4 acc[4][4] = {};
    float4 pa0, pa1;   // single prefetch set

    auto issueG = [&](int t) {
        const int k0 = t * 32;
        const int sl = t % 3;
        gload16(Bt + (size_t)arr * FDIM + k0 + akk * 8,         &Bs[sl][tid * 8]);
        gload16(Bt + (size_t)(128 + arr) * FDIM + k0 + akk * 8, &Bs[sl][(tid + 512) * 8]);
    };
    auto issueR = [&](int t) {
        const int k0 = t * 32;
        const float* s = A + (row0 + arr) * (size_t)FDIM + k0 + akk * 8;
        pa0 = *(const float4*)s;
        pa1 = *(const float4*)(s + 4);
    };
    auto finish = [&](int t) {
        const int sl = t % 3;
        u16x8 o = { f2b(pa0.x), f2b(pa0.y), f2b(pa0.z), f2b(pa0.w),
                    f2b(pa1.x), f2b(pa1.y), f2b(pa1.z), f2b(pa1.w) };
        *(u16x8*)&As[sl][tid * 8] = o;
    };

    issueG(0);
    issueR(0);
    issueG(1);
    wait_vm(2);
    finish(0);
    issueR(1);
    barrier_sync();

#pragma unroll
    for (int t = 0; t < NT; ++t) {
        if (t + 2 < NT) issueG(t + 2);

        const int sl = t % 3;
        __builtin_amdgcn_s_setprio(1);
        short8 af[4], bg[4];
#pragma unroll
        for (int i = 0; i < 4; i++) {
            af[i] = *(const short8*)&As[sl][frag_idx(wm * 64 + i * 16 + (lane & 15), lane >> 4)];
            bg[i] = *(const short8*)&Bs[sl][frag_idx(wn * 64 + i * 16 + (lane & 15), lane >> 4)];
        }
#pragma unroll
        for (int mi = 0; mi < 4; mi++)
#pragma unroll
            for (int ni = 0; ni < 4; ni++)
                acc[mi][ni] = __builtin_amdgcn_mfma_f32_16x16x32_bf16(af[mi], bg[ni], acc[mi][ni], 0, 0, 0);
        __builtin_amdgcn_s_setprio(0);

        if (t + 1 < NT) {
            wait_vm((t + 2 < NT) ? 2 : 0);
            finish(t + 1);
            if (t + 2 < NT) issueR(t + 2);
            barrier_sync();
        }
    }

#pragma unroll
    for (int mi = 0; mi < 4; mi++) {
        size_t rbase = row0 + wm * 64 + mi * 16 + (lane >> 4) * 4;
#pragma unroll
        for (int ni = 0; ni < 4; ni++) {
            int c = wn * 64 + ni * 16 + (lane & 15);
            float bb = bias[c];
            f32x4 v = acc[mi][ni];
#pragma unroll
            for (int r = 0; r < 4; r++)
                out[(rbase + r) * HH + c] = f2b(v[r] + bb);
        }
    }
}

// ---------------- upsample + residual add (bf16), in place on res (stage 5 only) ------------------
__global__ void upsample_add_kernel(unsigned short* __restrict__ res, const unsigned short* __restrict__ c,
                                    int Tc, int tlshift, int Rout)
{
    int idx = blockIdx.x * 256 + threadIdx.x;
    int r = idx >> 5, cc = (idx & 31) * 8;
    if (r >= Rout) return;
    int Tl = Tc * 2;
    int t  = r & (Tl - 1);
    int bq = r >> tlshift;
    int k  = t >> 1;
    size_t rc = (size_t)bq * Tc + k;
    float u[8];
    if (!(t & 1)) {
        u16x8 v = *(const u16x8*)(c + rc * HH + cc);
#pragma unroll
        for (int j = 0; j < 8; j++) u[j] = b2f(v[j]);
    } else if (k < Tc - 1) {
        u16x8 v0 = *(const u16x8*)(c + rc * HH + cc);
        u16x8 v1 = *(const u16x8*)(c + (rc + 1) * HH + cc);
#pragma unroll
        for (int j = 0; j < 8; j++) u[j] = 0.5f * (b2f(v0[j]) + b2f(v1[j]));
    } else {
        u16x8 v0 = *(const u16x8*)(c + rc * HH + cc);
        u16x8 vm = *(const u16x8*)(c + (rc - 1) * HH + cc);
#pragma unroll
        for (int j = 0; j < 8; j++) u[j] = 0.9f * b2f(v0[j]) + 0.1f * b2f(vm[j]);
    }
    u16x8 rv = *(const u16x8*)(res + (size_t)r * HH + cc);
    u16x8 o;
#pragma unroll
    for (int j = 0; j < 8; j++) o[j] = f2b(b2f(rv[j]) + u[j]);
    *(u16x8*)(res + (size_t)r * HH + cc) = o;
}

extern "C" void kernel_launch(void* const* d_in, const int* in_sizes, int n_in,
                              void* d_out, int out_size, void* d_ws, size_t ws_size,
                              hipStream_t stream)
{
    const float* x     = (const float*)d_in[0];
    const float* Wp    = (const float*)d_in[6];
    const float* bp    = (const float*)d_in[7];
    const float* Wself = (const float*)d_in[8];
    const float* Wnbr  = (const float*)d_in[9];
    const float* bconv = (const float*)d_in[10];
    const float* ln_g  = (const float*)d_in[11];
    const float* ln_b  = (const float*)d_in[12];
    float* out = (float*)d_out;

    char* p = (char*)d_ws;
    unsigned short* Wself_t = (unsigned short*)p; p += (size_t)12 * HH * HH * 2;
    unsigned short* Wnbr_t  = (unsigned short*)p; p += (size_t)12 * HH * HH * 2;
    unsigned short* Wp_t    = (unsigned short*)p; p += (size_t)HH * FDIM * 2;
    unsigned short* c0 = (unsigned short*)p; p += (size_t)R0 * HH * 2;   // 32 MiB
    unsigned short* c1 = (unsigned short*)p; p += (size_t)R1 * HH * 2;   // 16 MiB
    unsigned short* c2 = (unsigned short*)p; p += (size_t)R2 * HH * 2;   //  8 MiB
    unsigned short* c3 = (unsigned short*)p; p += (size_t)R3 * HH * 2;   //  4 MiB
    unsigned short* t1 = (unsigned short*)p; p += (size_t)R0 * HH * 2;   // 32 MiB
    if (ws_size < (size_t)(p - (char*)d_ws)) return;

    auto Ws = [&](int i) { return Wself_t + (size_t)i * HH * HH; };
    auto Wn = [&](int i) { return Wnbr_t  + (size_t)i * HH * HH; };

    // weight prep (single launch)
    transpose_all<<<1792, 256, 0, stream>>>(Wself, Wnbr, Wp, Wself_t, Wnbr_t, Wp_t);

    // projection: c0 = x @ Wp + bp
    proj_gemm<<<R0 / 128, 512, 0, stream>>>(x, Wp_t, bp, c0);

    // ---- down path (downsample fused into conv1 A-load; residual fused into conv2 LN epilogue) ----
    // stage 0 (R1 = 32768): BM=128 -> 256 blocks
    conv_fused<128, 1, 1, 0, 0><<<R1 / 128, 512, 0, stream>>>(c0, nullptr, nullptr, Ws(0), Wn(0),
        bconv + 0 * HH, nullptr, nullptr, t1, 2048, 0, 0);
    conv_fused<128, 0, 1, 1, 1><<<R1 / 128, 512, 0, stream>>>(t1, nullptr, c0, Ws(1), Wn(1),
        bconv + 1 * HH, ln_g + 0 * HH, ln_b + 0 * HH, c1, 2048, 0, 0);

    // stage 1 (R2 = 16384): BM=64 -> 256 blocks
    conv_fused<64, 1, 1, 0, 0><<<R2 / 64, 512, 0, stream>>>(c1, nullptr, nullptr, Ws(2), Wn(2),
        bconv + 2 * HH, nullptr, nullptr, t1, 1024, 0, 0);
    conv_fused<64, 0, 1, 1, 1><<<R2 / 64, 512, 0, stream>>>(t1, nullptr, c1, Ws(3), Wn(3),
        bconv + 3 * HH, ln_g + 1 * HH, ln_b + 1 * HH, c2, 1024, 0, 0);

    // stage 2 (R3 = 8192): BM=32 -> 256 blocks
    conv_fused<32, 1, 1, 0, 0><<<R3 / 32, 512, 0, stream>>>(c2, nullptr, nullptr, Ws(4), Wn(4),
        bconv + 4 * HH, nullptr, nullptr, t1, 512, 0, 0);
    conv_fused<32, 0, 1, 1, 1><<<R3 / 32, 512, 0, stream>>>(t1, nullptr, c2, Ws(5), Wn(5),
        bconv + 5 * HH, ln_g + 2 * HH, ln_b + 2 * HH, c3, 512, 0, 0);

    // ---- up path ----
    // stage 3 (R2): BM=64 -> 256 blocks
    conv_fused<64, 2, 0, 0, 0><<<R2 / 64, 512, 0, stream>>>(c2, c3, nullptr, Ws(6), nullptr,
        bconv + 6 * HH, nullptr, nullptr, t1, 1024, 512, 10);
    conv_fused<64, 0, 0, 1, 0><<<R2 / 64, 512, 0, stream>>>(t1, nullptr, nullptr, Ws(7), nullptr,
        bconv + 7 * HH, ln_g + 3 * HH, ln_b + 3 * HH, c2, 1024, 0, 0);

    // stage 4 (R1): BM=128 -> 256 blocks
    conv_fused<128, 2, 0, 0, 0><<<R1 / 128, 512, 0, stream>>>(c1, c2, nullptr, Ws(8), nullptr,
        bconv + 8 * HH, nullptr, nullptr, t1, 2048, 1024, 11);
    conv_fused<128, 0, 0, 1, 0><<<R1 / 128, 512, 0, stream>>>(t1, nullptr, nullptr, Ws(9), nullptr,
        bconv + 9 * HH, ln_g + 4 * HH, ln_b + 4 * HH, c1, 2048, 0, 0);

    // stage 5 (R0): materialized upsample; BM=128 convs (512 blocks)
    upsample_add_kernel<<<R0 / 8, 256, 0, stream>>>(c0, c1, 2048, 12, R0);
    conv_fused<128, 0, 1, 0, 0><<<R0 / 128, 512, 0, stream>>>(c0, nullptr, nullptr, Ws(10), Wn(10),
        bconv + 10 * HH, nullptr, nullptr, t1, 4096, 0, 0);
    conv_fused<128, 0, 1, 1, 2><<<R0 / 128, 512, 0, stream>>>(t1, nullptr, nullptr, Ws(11), Wn(11),
        bconv + 11 * HH, ln_g + 5 * HH, ln_b + 5 * HH, out, 4096, 0, 0);
}

// Round 15
// 353.435 us; speedup vs baseline: 1.1639x; 1.1639x over previous
//
#include <hip/hip_runtime.h>

#define HH 256

typedef __attribute__((ext_vector_type(8))) short short8;
typedef __attribute__((ext_vector_type(4))) float f32x4;
typedef __attribute__((ext_vector_type(4))) unsigned short u16x4;
typedef __attribute__((ext_vector_type(8))) unsigned short u16x8;

constexpr int NBATCH = 16;
constexpr int T0   = 4096;
constexpr int FDIM = 1024;
constexpr int R0   = NBATCH * T0;   // 65536
constexpr int R1   = R0 / 2;        // 32768
constexpr int R2   = R0 / 4;        // 16384
constexpr int R3   = R0 / 8;        // 8192

__device__ __forceinline__ float b2f(unsigned short u) {
    union { unsigned int i; float f; } v; v.i = ((unsigned int)u) << 16; return v.f;
}
__device__ __forceinline__ unsigned short f2b(float f) {
    union { float f; unsigned int i; } v; v.f = f;
    unsigned int r = v.i + 0x7fffu + ((v.i >> 16) & 1u);
    return (unsigned short)(r >> 16);
}
__device__ __forceinline__ void gload16(const void* g, void* l) {
    __builtin_amdgcn_global_load_lds((const __attribute__((address_space(1))) void*)g,
                                     (__attribute__((address_space(3))) void*)l, 16, 0, 0);
}
// raw barrier: drain LDS ops, then s_barrier (no vmcnt drain -- that's the point)
__device__ __forceinline__ void barrier_sync() {
    asm volatile("s_waitcnt lgkmcnt(0)\n\ts_barrier" ::: "memory");
}
// counted vmem wait; n folds to a constant under full unroll
__device__ __forceinline__ void wait_vm(int n) {
    switch (n) {
    case 2:  asm volatile("s_waitcnt vmcnt(2)"  ::: "memory"); break;
    case 3:  asm volatile("s_waitcnt vmcnt(3)"  ::: "memory"); break;
    case 4:  asm volatile("s_waitcnt vmcnt(4)"  ::: "memory"); break;
    case 5:  asm volatile("s_waitcnt vmcnt(5)"  ::: "memory"); break;
    case 6:  asm volatile("s_waitcnt vmcnt(6)"  ::: "memory"); break;
    default: asm volatile("s_waitcnt vmcnt(0)"  ::: "memory"); break;
    }
}
// LDS slot swizzle: slot s (16B granules) holds k-group ks = (s&3) ^ ((s>>3)&3) of row s>>2.
__device__ __forceinline__ int swz_ks(int chunk)        { return (chunk & 3) ^ ((chunk >> 3) & 3); }
__device__ __forceinline__ int frag_idx(int row, int g) { return (row * 4 + (g ^ ((row >> 1) & 3))) * 8; }

struct PVv { u16x8 v0, v1, v2, v3; };

// ---------------- weight transpose+convert (merged): fp32 [K][256] -> bf16 [256][K] --------------
__device__ __forceinline__ void transpose_tile(const float* __restrict__ src,
                                               unsigned short* __restrict__ dst,
                                               int K, int tilesPerMat, int bid, int tidx)
{
    int m = bid / tilesPerMat;
    int t = bid % tilesPerMat;
    int tr = t >> 3, tc = t & 7;
    const float* S = src + (size_t)m * K * HH;
    unsigned short* D = dst + (size_t)m * HH * K;
    __shared__ float tile[32][33];
    int x = tidx & 31, y = tidx >> 5;
#pragma unroll
    for (int i = y; i < 32; i += 8)
        tile[i][x] = S[(size_t)(tr * 32 + i) * HH + tc * 32 + x];
    __syncthreads();
#pragma unroll
    for (int i = y; i < 32; i += 8)
        D[(size_t)(tc * 32 + i) * K + tr * 32 + x] = f2b(tile[x][i]);
}

__global__ void transpose_all(const float* __restrict__ Wself, const float* __restrict__ Wnbr,
                              const float* __restrict__ Wp,
                              unsigned short* __restrict__ Ws_t, unsigned short* __restrict__ Wn_t,
                              unsigned short* __restrict__ Wp_t)
{
    int bid = blockIdx.x;
    if (bid < 768)       transpose_tile(Wself, Ws_t, HH,   64,  bid,        threadIdx.x);
    else if (bid < 1536) transpose_tile(Wnbr,  Wn_t, HH,   64,  bid - 768,  threadIdx.x);
    else                 transpose_tile(Wp,    Wp_t, FDIM, 256, bid - 1536, threadIdx.x);
}

// ================= unified conv GEMM, depth-2 counted-vmcnt pipeline (BM = 32 / 64 / 128) ========
// out = Aeff @ Bself [+ nbrmean(Aeff) @ Bnbr] + bias, then leaky (LNFUSE=0) or LN+leaky (LNFUSE=1).
// AMODE 0: Aeff=A[r]  1: A[2r] (fused downsample)  2: A[r]+upsample2(Cc)[r] (fused up+residual)
// OUT (LNFUSE=1 only) 0: bf16  1: bf16 + prev[2r] residual  2: fp32 final
template<int BM, int AMODE, int NBR, int LNFUSE, int OUT>
__launch_bounds__(512)
__global__ void conv_fused(const unsigned short* __restrict__ A,
                           const unsigned short* __restrict__ Cc,
                           const unsigned short* __restrict__ prev,
                           const unsigned short* __restrict__ Bself,
                           const unsigned short* __restrict__ Bnbr,
                           const float* __restrict__ bias,
                           const float* __restrict__ lng,
                           const float* __restrict__ lnb,
                           void* __restrict__ dstv,
                           int Tl, int Tc, int tlshift)
{
    constexpr int NT = NBR ? 16 : 8;
    constexpr int MF = (BM + 31) / 32;   // m-frags per wave (BM=32 -> 1)
    constexpr int WROWS = BM / 2;        // rows per wave-m half
    __shared__ unsigned short As[3][BM * 32];
    __shared__ unsigned short Bs[3][256 * 32];
    __shared__ float lnred[LNFUSE ? BM : 1][8];

    const int tid  = threadIdx.x;
    const int lane = tid & 63;
    const int w    = tid >> 6;
    const int wm   = w & 1, wn = w >> 1;
    const long row0 = (long)blockIdx.x * BM;

    const bool hasA   = (tid < BM * 4);       // threads that stage A
    const bool hasA_w = (w < (BM * 4) / 64);  // wave-uniform version (for vmcnt counts)
    const int arr = tid >> 2;                 // staging row
    const int akk = swz_ks(tid);
    const long gr = row0 + (hasA ? arr : 0);

    // ---- producer precompute ----
    float ca = 0.f, cb = 0.f; size_t rc0 = 0, rc1 = 0;
    if (AMODE == 2) {
        int t = (int)(gr & (long)(Tl - 1));
        long bq = gr >> tlshift;
        int k = t >> 1;
        rc0 = (size_t)bq * Tc + k;
        if (!(t & 1))        { ca = 1.0f; cb = 0.0f; rc1 = rc0; }
        else if (k < Tc - 1) { ca = 0.5f; cb = 0.5f; rc1 = rc0 + 1; }
        else                 { ca = 0.9f; cb = 0.1f; rc1 = rc0 - 1; }
    }
    float vinv = 1.f;
    float cf0 = 0.f, cf1 = 0.f, cf2 = 0.f, cf3 = 0.f;
    size_t nrow0 = 0, nrow1 = 0, nrow2 = 0, nrow3 = 0;
    if (NBR) {
        const int offs[4] = {-2, -1, 1, 2};
        int t = (int)(gr & (long)(Tl - 1));
        int cnt = 0;
        float cf[4]; size_t nr[4];
#pragma unroll
        for (int oi = 0; oi < 4; oi++) {
            int tn = t + offs[oi];
            bool v = (tn >= 0 && tn < Tl);
            cnt += v ? 1 : 0;
            int tcl = tn < 0 ? 0 : (tn > Tl - 1 ? Tl - 1 : tn);
            long r = gr - t + tcl;
            nr[oi] = (size_t)((AMODE == 1) ? 2 * r : r) * HH;
            cf[oi] = v ? 1.f : 0.f;
        }
        vinv = 1.f / (float)cnt;
        cf0 = cf[0]; cf1 = cf[1]; cf2 = cf[2]; cf3 = cf[3];
        nrow0 = nr[0]; nrow1 = nr[1]; nrow2 = nr[2]; nrow3 = nr[3];
    }

    f32x4 acc[MF][4] = {};
    PVv pvE = {}, pvO = {};

    auto Lof = [&](int t) -> int {
        if (!hasA_w) return 2;
        const int seg = (NBR && t >= 8) ? 1 : 0;
        return seg ? 6 : (AMODE == 2 ? 5 : 3);
    };
    auto issueB = [&](int t) {
        const int seg = (NBR && t >= 8) ? 1 : 0;
        const int k0 = (t & 7) * 32;
        const int sl = t % 3;
        const unsigned short* __restrict__ Bm = seg ? Bnbr : Bself;
        gload16(Bm + (size_t)arr * HH + k0 + akk * 8,         &Bs[sl][tid * 8]);
        gload16(Bm + (size_t)(128 + arr) * HH + k0 + akk * 8, &Bs[sl][(tid + 512) * 8]);
    };
    auto issueA = [&](int t, PVv& pv) {
        if (!hasA) return;
        const int seg = (NBR && t >= 8) ? 1 : 0;
        const int k0 = (t & 7) * 32;
        const int sl = t % 3;
        if (seg == 0) {
            if (AMODE == 0) {
                gload16(A + (size_t)gr * HH + k0 + akk * 8, &As[sl][tid * 8]);
            } else if (AMODE == 1) {
                gload16(A + (size_t)(2 * gr) * HH + k0 + akk * 8, &As[sl][tid * 8]);
            } else {
                pv.v0 = *(const u16x8*)(A + (size_t)gr * HH + k0 + akk * 8);
                pv.v1 = *(const u16x8*)(Cc + rc0 * HH + k0 + akk * 8);
                pv.v2 = *(const u16x8*)(Cc + rc1 * HH + k0 + akk * 8);
            }
        } else {
            pv.v0 = *(const u16x8*)(A + nrow0 + k0 + akk * 8);
            pv.v1 = *(const u16x8*)(A + nrow1 + k0 + akk * 8);
            pv.v2 = *(const u16x8*)(A + nrow2 + k0 + akk * 8);
            pv.v3 = *(const u16x8*)(A + nrow3 + k0 + akk * 8);
        }
    };
    auto finishA = [&](int t, PVv& pv) {
        if (!hasA) return;
        const int seg = (NBR && t >= 8) ? 1 : 0;
        const int sl = t % 3;
        if (seg == 0) {
            if (AMODE == 2) {
                u16x8 o;
#pragma unroll
                for (int j = 0; j < 8; j++)
                    o[j] = f2b(b2f(pv.v0[j]) + ca * b2f(pv.v1[j]) + cb * b2f(pv.v2[j]));
                *(u16x8*)&As[sl][tid * 8] = o;
            }
        } else {
            u16x8 o;
#pragma unroll
            for (int j = 0; j < 8; j++) {
                float a = cf0 * b2f(pv.v0[j]) + cf1 * b2f(pv.v1[j])
                        + cf2 * b2f(pv.v2[j]) + cf3 * b2f(pv.v3[j]);
                o[j] = f2b(a * vinv);
            }
            *(u16x8*)&As[sl][tid * 8] = o;
        }
    };

    issueB(0); issueA(0, pvE);
    issueB(1); issueA(1, pvO);
    wait_vm(Lof(1));
    finishA(0, pvE);
    barrier_sync();

#pragma unroll
    for (int t = 0; t < NT; ++t) {
        if (t + 2 < NT) {
            issueB(t + 2);
            if (((t + 2) & 1) == 0) issueA(t + 2, pvE); else issueA(t + 2, pvO);
        }

        const int sl = t % 3;
        __builtin_amdgcn_s_setprio(1);
        short8 af[MF], bg[4];
#pragma unroll
        for (int i = 0; i < MF; i++)
            af[i] = *(const short8*)&As[sl][frag_idx(wm * WROWS + i * 16 + (lane & 15), lane >> 4)];
#pragma unroll
        for (int i = 0; i < 4; i++)
            bg[i] = *(const short8*)&Bs[sl][frag_idx(wn * 64 + i * 16 + (lane & 15), lane >> 4)];
#pragma unroll
        for (int mi = 0; mi < MF; mi++)
#pragma unroll
            for (int ni = 0; ni < 4; ni++)
                acc[mi][ni] = __builtin_amdgcn_mfma_f32_16x16x32_bf16(af[mi], bg[ni], acc[mi][ni], 0, 0, 0);
        __builtin_amdgcn_s_setprio(0);

        if (t + 1 < NT) {
            wait_vm((t + 2 < NT) ? Lof(t + 2) : 0);
            if (((t + 1) & 1) == 0) finishA(t + 1, pvE); else finishA(t + 1, pvO);
            barrier_sync();
        }
    }

    // ---- epilogue ----
    if (LNFUSE == 0) {
        unsigned short* outp = (unsigned short*)dstv;
#pragma unroll
        for (int mi = 0; mi < MF; mi++) {
            size_t rbase = (size_t)row0 + wm * WROWS + mi * 16 + (lane >> 4) * 4;
#pragma unroll
            for (int ni = 0; ni < 4; ni++) {
                int c = wn * 64 + ni * 16 + (lane & 15);
                float bb = bias[c];
                f32x4 v = acc[mi][ni];
#pragma unroll
                for (int r = 0; r < 4; r++) {
                    float t = v[r] + bb;
                    t = (t >= 0.f) ? t : 0.2f * t;
                    outp[(rbase + r) * HH + c] = f2b(t);
                }
            }
        }
    } else {
        float bb[4];
#pragma unroll
        for (int ni = 0; ni < 4; ni++) bb[ni] = bias[wn * 64 + ni * 16 + (lane & 15)];

#pragma unroll
        for (int mi = 0; mi < MF; mi++) {
#pragma unroll
            for (int r = 0; r < 4; r++) {
                float s = 0.f, q = 0.f;
#pragma unroll
                for (int ni = 0; ni < 4; ni++) {
                    float v = acc[mi][ni][r] + bb[ni];
                    s += v; q += v * v;
                }
                s += __shfl_xor(s, 1); q += __shfl_xor(q, 1);
                s += __shfl_xor(s, 2); q += __shfl_xor(q, 2);
                s += __shfl_xor(s, 4); q += __shfl_xor(q, 4);
                s += __shfl_xor(s, 8); q += __shfl_xor(q, 8);
                if ((lane & 15) == 0) {
                    int row = wm * WROWS + mi * 16 + (lane >> 4) * 4 + r;
                    lnred[row][wn]     = s;
                    lnred[row][4 + wn] = q;
                }
            }
        }
        __syncthreads();

        float gv[4], bv[4];
#pragma unroll
        for (int ni = 0; ni < 4; ni++) {
            int c = wn * 64 + ni * 16 + (lane & 15);
            gv[ni] = lng[c]; bv[ni] = lnb[c];
        }

#pragma unroll
        for (int mi = 0; mi < MF; mi++) {
#pragma unroll
            for (int r = 0; r < 4; r++) {
                int row = wm * WROWS + mi * 16 + (lane >> 4) * 4 + r;
                float s = lnred[row][0] + lnred[row][1] + lnred[row][2] + lnred[row][3];
                float q = lnred[row][4] + lnred[row][5] + lnred[row][6] + lnred[row][7];
                float mu  = s * (1.0f / HH);
                float var = q * (1.0f / HH) - mu * mu;
                float inv = rsqrtf(var + 1e-5f);
                size_t grow = (size_t)row0 + row;
#pragma unroll
                for (int ni = 0; ni < 4; ni++) {
                    int c = wn * 64 + ni * 16 + (lane & 15);
                    float v = acc[mi][ni][r] + bb[ni];
                    float y = (v - mu) * inv * gv[ni] + bv[ni];
                    y = (y >= 0.f) ? y : 0.2f * y;
                    if (OUT == 2) {
                        ((float*)dstv)[grow * HH + c] = y;
                    } else {
                        if (OUT == 1) y += b2f(prev[(2 * grow) * HH + c]);
                        ((unsigned short*)dstv)[grow * HH + c] = f2b(y);
                    }
                }
            }
        }
    }
}

// ---------------- projection GEMM, same depth-2 pipeline: A fp32 -> bf16 producer -----------------
__launch_bounds__(512)
__global__ void proj_gemm(const float* __restrict__ A, const unsigned short* __restrict__ Bt,
                          const float* __restrict__ bias, unsigned short* __restrict__ out)
{
    constexpr int NT = FDIM / 32;   // 32
    __shared__ unsigned short As[3][128 * 32];
    __shared__ unsigned short Bs[3][256 * 32];
    const int tid  = threadIdx.x;
    const int lane = tid & 63;
    const int w    = tid >> 6;
    const int wm   = w & 1, wn = w >> 1;
    const size_t row0 = (size_t)blockIdx.x * 128;

    const int arr = tid >> 2;
    const int akk = swz_ks(tid);

    f32x4 acc[4][4] = {};
    float4 paE0, paE1, paO0, paO1;

    auto issue = [&](int t, float4& p0, float4& p1) {
        const int k0 = t * 32;
        const int sl = t % 3;
        gload16(Bt + (size_t)arr * FDIM + k0 + akk * 8,         &Bs[sl][tid * 8]);
        gload16(Bt + (size_t)(128 + arr) * FDIM + k0 + akk * 8, &Bs[sl][(tid + 512) * 8]);
        const float* s = A + (row0 + arr) * (size_t)FDIM + k0 + akk * 8;
        p0 = *(const float4*)s;
        p1 = *(const float4*)(s + 4);
    };
    auto finish = [&](int t, float4& p0, float4& p1) {
        const int sl = t % 3;
        u16x8 o = { f2b(p0.x), f2b(p0.y), f2b(p0.z), f2b(p0.w),
                    f2b(p1.x), f2b(p1.y), f2b(p1.z), f2b(p1.w) };
        *(u16x8*)&As[sl][tid * 8] = o;
    };

    issue(0, paE0, paE1);
    issue(1, paO0, paO1);
    wait_vm(4);
    finish(0, paE0, paE1);
    barrier_sync();

#pragma unroll
    for (int t = 0; t < NT; ++t) {
        if (t + 2 < NT) {
            if (((t + 2) & 1) == 0) issue(t + 2, paE0, paE1); else issue(t + 2, paO0, paO1);
        }

        const int sl = t % 3;
        __builtin_amdgcn_s_setprio(1);
        short8 af[4], bg[4];
#pragma unroll
        for (int i = 0; i < 4; i++) {
            af[i] = *(const short8*)&As[sl][frag_idx(wm * 64 + i * 16 + (lane & 15), lane >> 4)];
            bg[i] = *(const short8*)&Bs[sl][frag_idx(wn * 64 + i * 16 + (lane & 15), lane >> 4)];
        }
#pragma unroll
        for (int mi = 0; mi < 4; mi++)
#pragma unroll
            for (int ni = 0; ni < 4; ni++)
                acc[mi][ni] = __builtin_amdgcn_mfma_f32_16x16x32_bf16(af[mi], bg[ni], acc[mi][ni], 0, 0, 0);
        __builtin_amdgcn_s_setprio(0);

        if (t + 1 < NT) {
            wait_vm((t + 2 < NT) ? 4 : 0);
            if (((t + 1) & 1) == 0) finish(t + 1, paE0, paE1); else finish(t + 1, paO0, paO1);
            barrier_sync();
        }
    }

#pragma unroll
    for (int mi = 0; mi < 4; mi++) {
        size_t rbase = row0 + wm * 64 + mi * 16 + (lane >> 4) * 4;
#pragma unroll
        for (int ni = 0; ni < 4; ni++) {
            int c = wn * 64 + ni * 16 + (lane & 15);
            float bb = bias[c];
            f32x4 v = acc[mi][ni];
#pragma unroll
            for (int r = 0; r < 4; r++)
                out[(rbase + r) * HH + c] = f2b(v[r] + bb);
        }
    }
}

// ---------------- upsample + residual add (bf16), in place on res (stage 5 only) ------------------
__global__ void upsample_add_kernel(unsigned short* __restrict__ res, const unsigned short* __restrict__ c,
                                    int Tc, int tlshift, int Rout)
{
    int idx = blockIdx.x * 256 + threadIdx.x;
    int r = idx >> 5, cc = (idx & 31) * 8;
    if (r >= Rout) return;
    int Tl = Tc * 2;
    int t  = r & (Tl - 1);
    int bq = r >> tlshift;
    int k  = t >> 1;
    size_t rc = (size_t)bq * Tc + k;
    float u[8];
    if (!(t & 1)) {
        u16x8 v = *(const u16x8*)(c + rc * HH + cc);
#pragma unroll
        for (int j = 0; j < 8; j++) u[j] = b2f(v[j]);
    } else if (k < Tc - 1) {
        u16x8 v0 = *(const u16x8*)(c + rc * HH + cc);
        u16x8 v1 = *(const u16x8*)(c + (rc + 1) * HH + cc);
#pragma unroll
        for (int j = 0; j < 8; j++) u[j] = 0.5f * (b2f(v0[j]) + b2f(v1[j]));
    } else {
        u16x8 v0 = *(const u16x8*)(c + rc * HH + cc);
        u16x8 vm = *(const u16x8*)(c + (rc - 1) * HH + cc);
#pragma unroll
        for (int j = 0; j < 8; j++) u[j] = 0.9f * b2f(v0[j]) + 0.1f * b2f(vm[j]);
    }
    u16x8 rv = *(const u16x8*)(res + (size_t)r * HH + cc);
    u16x8 o;
#pragma unroll
    for (int j = 0; j < 8; j++) o[j] = f2b(b2f(rv[j]) + u[j]);
    *(u16x8*)(res + (size_t)r * HH + cc) = o;
}

extern "C" void kernel_launch(void* const* d_in, const int* in_sizes, int n_in,
                              void* d_out, int out_size, void* d_ws, size_t ws_size,
                              hipStream_t stream)
{
    const float* x     = (const float*)d_in[0];
    const float* Wp    = (const float*)d_in[6];
    const float* bp    = (const float*)d_in[7];
    const float* Wself = (const float*)d_in[8];
    const float* Wnbr  = (const float*)d_in[9];
    const float* bconv = (const float*)d_in[10];
    const float* ln_g  = (const float*)d_in[11];
    const float* ln_b  = (const float*)d_in[12];
    float* out = (float*)d_out;

    char* p = (char*)d_ws;
    unsigned short* Wself_t = (unsigned short*)p; p += (size_t)12 * HH * HH * 2;
    unsigned short* Wnbr_t  = (unsigned short*)p; p += (size_t)12 * HH * HH * 2;
    unsigned short* Wp_t    = (unsigned short*)p; p += (size_t)HH * FDIM * 2;
    unsigned short* c0 = (unsigned short*)p; p += (size_t)R0 * HH * 2;   // 32 MiB
    unsigned short* c1 = (unsigned short*)p; p += (size_t)R1 * HH * 2;   // 16 MiB
    unsigned short* c2 = (unsigned short*)p; p += (size_t)R2 * HH * 2;   //  8 MiB
    unsigned short* c3 = (unsigned short*)p; p += (size_t)R3 * HH * 2;   //  4 MiB
    unsigned short* t1 = (unsigned short*)p; p += (size_t)R0 * HH * 2;   // 32 MiB
    if (ws_size < (size_t)(p - (char*)d_ws)) return;

    auto Ws = [&](int i) { return Wself_t + (size_t)i * HH * HH; };
    auto Wn = [&](int i) { return Wnbr_t  + (size_t)i * HH * HH; };

    // weight prep (single launch)
    transpose_all<<<1792, 256, 0, stream>>>(Wself, Wnbr, Wp, Wself_t, Wnbr_t, Wp_t);

    // projection: c0 = x @ Wp + bp
    proj_gemm<<<R0 / 128, 512, 0, stream>>>(x, Wp_t, bp, c0);

    // ---- down path (downsample fused into conv1 A-load; residual fused into conv2 LN epilogue) ----
    // stage 0 (R1 = 32768): BM=128 -> 256 blocks
    conv_fused<128, 1, 1, 0, 0><<<R1 / 128, 512, 0, stream>>>(c0, nullptr, nullptr, Ws(0), Wn(0),
        bconv + 0 * HH, nullptr, nullptr, t1, 2048, 0, 0);
    conv_fused<128, 0, 1, 1, 1><<<R1 / 128, 512, 0, stream>>>(t1, nullptr, c0, Ws(1), Wn(1),
        bconv + 1 * HH, ln_g + 0 * HH, ln_b + 0 * HH, c1, 2048, 0, 0);

    // stage 1 (R2 = 16384): BM=64 -> 256 blocks
    conv_fused<64, 1, 1, 0, 0><<<R2 / 64, 512, 0, stream>>>(c1, nullptr, nullptr, Ws(2), Wn(2),
        bconv + 2 * HH, nullptr, nullptr, t1, 1024, 0, 0);
    conv_fused<64, 0, 1, 1, 1><<<R2 / 64, 512, 0, stream>>>(t1, nullptr, c1, Ws(3), Wn(3),
        bconv + 3 * HH, ln_g + 1 * HH, ln_b + 1 * HH, c2, 1024, 0, 0);

    // stage 2 (R3 = 8192): BM=32 -> 256 blocks
    conv_fused<32, 1, 1, 0, 0><<<R3 / 32, 512, 0, stream>>>(c2, nullptr, nullptr, Ws(4), Wn(4),
        bconv + 4 * HH, nullptr, nullptr, t1, 512, 0, 0);
    conv_fused<32, 0, 1, 1, 1><<<R3 / 32, 512, 0, stream>>>(t1, nullptr, c2, Ws(5), Wn(5),
        bconv + 5 * HH, ln_g + 2 * HH, ln_b + 2 * HH, c3, 512, 0, 0);

    // ---- up path ----
    // stage 3 (R2): BM=64 -> 256 blocks
    conv_fused<64, 2, 0, 0, 0><<<R2 / 64, 512, 0, stream>>>(c2, c3, nullptr, Ws(6), nullptr,
        bconv + 6 * HH, nullptr, nullptr, t1, 1024, 512, 10);
    conv_fused<64, 0, 0, 1, 0><<<R2 / 64, 512, 0, stream>>>(t1, nullptr, nullptr, Ws(7), nullptr,
        bconv + 7 * HH, ln_g + 3 * HH, ln_b + 3 * HH, c2, 1024, 0, 0);

    // stage 4 (R1): BM=128 -> 256 blocks
    conv_fused<128, 2, 0, 0, 0><<<R1 / 128, 512, 0, stream>>>(c1, c2, nullptr, Ws(8), nullptr,
        bconv + 8 * HH, nullptr, nullptr, t1, 2048, 1024, 11);
    conv_fused<128, 0, 0, 1, 0><<<R1 / 128, 512, 0, stream>>>(t1, nullptr, nullptr, Ws(9), nullptr,
        bconv + 9 * HH, ln_g + 4 * HH, ln_b + 4 * HH, c1, 2048, 0, 0);

    // stage 5 (R0): materialized upsample; BM=128 convs (512 blocks)
    upsample_add_kernel<<<R0 / 8, 256, 0, stream>>>(c0, c1, 2048, 12, R0);
    conv_fused<128, 0, 1, 0, 0><<<R0 / 128, 512, 0, stream>>>(c0, nullptr, nullptr, Ws(10), Wn(10),
        bconv + 10 * HH, nullptr, nullptr, t1, 4096, 0, 0);
    conv_fused<128, 0, 1, 1, 2><<<R0 / 128, 512, 0, stream>>>(t1, nullptr, nullptr, Ws(11), Wn(11),
        bconv + 11 * HH, ln_g + 5 * HH, ln_b + 5 * HH, out, 4096, 0, 0);
}

// Round 16
// 352.905 us; speedup vs baseline: 1.1656x; 1.0015x over previous
//
#include <hip/hip_runtime.h>

#define HH 256

typedef __attribute__((ext_vector_type(8))) short short8;
typedef __attribute__((ext_vector_type(4))) float f32x4;
typedef __attribute__((ext_vector_type(4))) unsigned short u16x4;
typedef __attribute__((ext_vector_type(8))) unsigned short u16x8;

constexpr int NBATCH = 16;
constexpr int T0   = 4096;
constexpr int FDIM = 1024;
constexpr int R0   = NBATCH * T0;   // 65536
constexpr int R1   = R0 / 2;        // 32768
constexpr int R2   = R0 / 4;        // 16384
constexpr int R3   = R0 / 8;        // 8192

__device__ __forceinline__ float b2f(unsigned short u) {
    union { unsigned int i; float f; } v; v.i = ((unsigned int)u) << 16; return v.f;
}
__device__ __forceinline__ unsigned short f2b(float f) {
    union { float f; unsigned int i; } v; v.f = f;
    unsigned int r = v.i + 0x7fffu + ((v.i >> 16) & 1u);
    return (unsigned short)(r >> 16);
}
__device__ __forceinline__ void gload16(const void* g, void* l) {
    __builtin_amdgcn_global_load_lds((const __attribute__((address_space(1))) void*)g,
                                     (__attribute__((address_space(3))) void*)l, 16, 0, 0);
}
// raw barrier: drain LDS ops, then s_barrier (no vmcnt drain -- that's the point)
__device__ __forceinline__ void barrier_sync() {
    asm volatile("s_waitcnt lgkmcnt(0)\n\ts_barrier" ::: "memory");
}
// counted vmem wait; n folds to a constant under full unroll
__device__ __forceinline__ void wait_vm(int n) {
    switch (n) {
    case 2:  asm volatile("s_waitcnt vmcnt(2)"  ::: "memory"); break;
    case 3:  asm volatile("s_waitcnt vmcnt(3)"  ::: "memory"); break;
    case 4:  asm volatile("s_waitcnt vmcnt(4)"  ::: "memory"); break;
    case 5:  asm volatile("s_waitcnt vmcnt(5)"  ::: "memory"); break;
    case 6:  asm volatile("s_waitcnt vmcnt(6)"  ::: "memory"); break;
    default: asm volatile("s_waitcnt vmcnt(0)"  ::: "memory"); break;
    }
}
// LDS slot swizzle: slot s (16B granules) holds k-group ks = (s&3) ^ ((s>>3)&3) of row s>>2.
__device__ __forceinline__ int swz_ks(int chunk)        { return (chunk & 3) ^ ((chunk >> 3) & 3); }
__device__ __forceinline__ int frag_idx(int row, int g) { return (row * 4 + (g ^ ((row >> 1) & 3))) * 8; }
// A2 tile (fused up-stage): [row][256] bf16, granule swizzle g^(row&31); elem index
__device__ __forceinline__ int a2_idx(int row, int g)   { return (row * 32 + (g ^ (row & 31))) * 8; }

struct PVv { u16x8 v0, v1, v2, v3; };

// ---------------- weight transpose+convert (merged): fp32 [K][256] -> bf16 [256][K] --------------
__device__ __forceinline__ void transpose_tile(const float* __restrict__ src,
                                               unsigned short* __restrict__ dst,
                                               int K, int tilesPerMat, int bid, int tidx)
{
    int m = bid / tilesPerMat;
    int t = bid % tilesPerMat;
    int tr = t >> 3, tc = t & 7;
    const float* S = src + (size_t)m * K * HH;
    unsigned short* D = dst + (size_t)m * HH * K;
    __shared__ float tile[32][33];
    int x = tidx & 31, y = tidx >> 5;
#pragma unroll
    for (int i = y; i < 32; i += 8)
        tile[i][x] = S[(size_t)(tr * 32 + i) * HH + tc * 32 + x];
    __syncthreads();
#pragma unroll
    for (int i = y; i < 32; i += 8)
        D[(size_t)(tc * 32 + i) * K + tr * 32 + x] = f2b(tile[x][i]);
}

__global__ void transpose_all(const float* __restrict__ Wself, const float* __restrict__ Wnbr,
                              const float* __restrict__ Wp,
                              unsigned short* __restrict__ Ws_t, unsigned short* __restrict__ Wn_t,
                              unsigned short* __restrict__ Wp_t)
{
    int bid = blockIdx.x;
    if (bid < 768)       transpose_tile(Wself, Ws_t, HH,   64,  bid,        threadIdx.x);
    else if (bid < 1536) transpose_tile(Wnbr,  Wn_t, HH,   64,  bid - 768,  threadIdx.x);
    else                 transpose_tile(Wp,    Wp_t, FDIM, 256, bid - 1536, threadIdx.x);
}

// ================= unified conv GEMM, depth-2 counted-vmcnt pipeline (BM = 32 / 64 / 128) ========
// out = Aeff @ Bself [+ nbrmean(Aeff) @ Bnbr] + bias, then leaky (LNFUSE=0) or LN+leaky (LNFUSE=1).
// AMODE 0: Aeff=A[r]  1: A[2r] (fused downsample)  2: A[r]+upsample2(Cc)[r] (fused up+residual)
// OUT (LNFUSE=1 only) 0: bf16  1: bf16 + prev[2r] residual  2: fp32 final
template<int BM, int AMODE, int NBR, int LNFUSE, int OUT>
__launch_bounds__(512)
__global__ void conv_fused(const unsigned short* __restrict__ A,
                           const unsigned short* __restrict__ Cc,
                           const unsigned short* __restrict__ prev,
                           const unsigned short* __restrict__ Bself,
                           const unsigned short* __restrict__ Bnbr,
                           const float* __restrict__ bias,
                           const float* __restrict__ lng,
                           const float* __restrict__ lnb,
                           void* __restrict__ dstv,
                           int Tl, int Tc, int tlshift)
{
    constexpr int NT = NBR ? 16 : 8;
    constexpr int MF = (BM + 31) / 32;   // m-frags per wave (BM=32 -> 1)
    constexpr int WROWS = BM / 2;        // rows per wave-m half
    __shared__ unsigned short As[3][BM * 32];
    __shared__ unsigned short Bs[3][256 * 32];
    __shared__ float lnred[LNFUSE ? BM : 1][8];

    const int tid  = threadIdx.x;
    const int lane = tid & 63;
    const int w    = tid >> 6;
    const int wm   = w & 1, wn = w >> 1;
    const long row0 = (long)blockIdx.x * BM;

    const bool hasA   = (tid < BM * 4);       // threads that stage A
    const bool hasA_w = (w < (BM * 4) / 64);  // wave-uniform version (for vmcnt counts)
    const int arr = tid >> 2;                 // staging row
    const int akk = swz_ks(tid);
    const long gr = row0 + (hasA ? arr : 0);

    // ---- producer precompute ----
    float ca = 0.f, cb = 0.f; size_t rc0 = 0, rc1 = 0;
    if (AMODE == 2) {
        int t = (int)(gr & (long)(Tl - 1));
        long bq = gr >> tlshift;
        int k = t >> 1;
        rc0 = (size_t)bq * Tc + k;
        if (!(t & 1))        { ca = 1.0f; cb = 0.0f; rc1 = rc0; }
        else if (k < Tc - 1) { ca = 0.5f; cb = 0.5f; rc1 = rc0 + 1; }
        else                 { ca = 0.9f; cb = 0.1f; rc1 = rc0 - 1; }
    }
    float vinv = 1.f;
    float cf0 = 0.f, cf1 = 0.f, cf2 = 0.f, cf3 = 0.f;
    size_t nrow0 = 0, nrow1 = 0, nrow2 = 0, nrow3 = 0;
    if (NBR) {
        const int offs[4] = {-2, -1, 1, 2};
        int t = (int)(gr & (long)(Tl - 1));
        int cnt = 0;
        float cf[4]; size_t nr[4];
#pragma unroll
        for (int oi = 0; oi < 4; oi++) {
            int tn = t + offs[oi];
            bool v = (tn >= 0 && tn < Tl);
            cnt += v ? 1 : 0;
            int tcl = tn < 0 ? 0 : (tn > Tl - 1 ? Tl - 1 : tn);
            long r = gr - t + tcl;
            nr[oi] = (size_t)((AMODE == 1) ? 2 * r : r) * HH;
            cf[oi] = v ? 1.f : 0.f;
        }
        vinv = 1.f / (float)cnt;
        cf0 = cf[0]; cf1 = cf[1]; cf2 = cf[2]; cf3 = cf[3];
        nrow0 = nr[0]; nrow1 = nr[1]; nrow2 = nr[2]; nrow3 = nr[3];
    }

    f32x4 acc[MF][4] = {};
    PVv pvE = {}, pvO = {};

    auto Lof = [&](int t) -> int {
        if (!hasA_w) return 2;
        const int seg = (NBR && t >= 8) ? 1 : 0;
        return seg ? 6 : (AMODE == 2 ? 5 : 3);
    };
    auto issueB = [&](int t) {
        const int seg = (NBR && t >= 8) ? 1 : 0;
        const int k0 = (t & 7) * 32;
        const int sl = t % 3;
        const unsigned short* __restrict__ Bm = seg ? Bnbr : Bself;
        gload16(Bm + (size_t)arr * HH + k0 + akk * 8,         &Bs[sl][tid * 8]);
        gload16(Bm + (size_t)(128 + arr) * HH + k0 + akk * 8, &Bs[sl][(tid + 512) * 8]);
    };
    auto issueA = [&](int t, PVv& pv) {
        if (!hasA) return;
        const int seg = (NBR && t >= 8) ? 1 : 0;
        const int k0 = (t & 7) * 32;
        const int sl = t % 3;
        if (seg == 0) {
            if (AMODE == 0) {
                gload16(A + (size_t)gr * HH + k0 + akk * 8, &As[sl][tid * 8]);
            } else if (AMODE == 1) {
                gload16(A + (size_t)(2 * gr) * HH + k0 + akk * 8, &As[sl][tid * 8]);
            } else {
                pv.v0 = *(const u16x8*)(A + (size_t)gr * HH + k0 + akk * 8);
                pv.v1 = *(const u16x8*)(Cc + rc0 * HH + k0 + akk * 8);
                pv.v2 = *(const u16x8*)(Cc + rc1 * HH + k0 + akk * 8);
            }
        } else {
            pv.v0 = *(const u16x8*)(A + nrow0 + k0 + akk * 8);
            pv.v1 = *(const u16x8*)(A + nrow1 + k0 + akk * 8);
            pv.v2 = *(const u16x8*)(A + nrow2 + k0 + akk * 8);
            pv.v3 = *(const u16x8*)(A + nrow3 + k0 + akk * 8);
        }
    };
    auto finishA = [&](int t, PVv& pv) {
        if (!hasA) return;
        const int seg = (NBR && t >= 8) ? 1 : 0;
        const int sl = t % 3;
        if (seg == 0) {
            if (AMODE == 2) {
                u16x8 o;
#pragma unroll
                for (int j = 0; j < 8; j++)
                    o[j] = f2b(b2f(pv.v0[j]) + ca * b2f(pv.v1[j]) + cb * b2f(pv.v2[j]));
                *(u16x8*)&As[sl][tid * 8] = o;
            }
        } else {
            u16x8 o;
#pragma unroll
            for (int j = 0; j < 8; j++) {
                float a = cf0 * b2f(pv.v0[j]) + cf1 * b2f(pv.v1[j])
                        + cf2 * b2f(pv.v2[j]) + cf3 * b2f(pv.v3[j]);
                o[j] = f2b(a * vinv);
            }
            *(u16x8*)&As[sl][tid * 8] = o;
        }
    };

    issueB(0); issueA(0, pvE);
    issueB(1); issueA(1, pvO);
    wait_vm(Lof(1));
    finishA(0, pvE);
    barrier_sync();

#pragma unroll
    for (int t = 0; t < NT; ++t) {
        if (t + 2 < NT) {
            issueB(t + 2);
            if (((t + 2) & 1) == 0) issueA(t + 2, pvE); else issueA(t + 2, pvO);
        }

        const int sl = t % 3;
        __builtin_amdgcn_s_setprio(1);
        short8 af[MF], bg[4];
#pragma unroll
        for (int i = 0; i < MF; i++)
            af[i] = *(const short8*)&As[sl][frag_idx(wm * WROWS + i * 16 + (lane & 15), lane >> 4)];
#pragma unroll
        for (int i = 0; i < 4; i++)
            bg[i] = *(const short8*)&Bs[sl][frag_idx(wn * 64 + i * 16 + (lane & 15), lane >> 4)];
#pragma unroll
        for (int mi = 0; mi < MF; mi++)
#pragma unroll
            for (int ni = 0; ni < 4; ni++)
                acc[mi][ni] = __builtin_amdgcn_mfma_f32_16x16x32_bf16(af[mi], bg[ni], acc[mi][ni], 0, 0, 0);
        __builtin_amdgcn_s_setprio(0);

        if (t + 1 < NT) {
            wait_vm((t + 2 < NT) ? Lof(t + 2) : 0);
            if (((t + 1) & 1) == 0) finishA(t + 1, pvE); else finishA(t + 1, pvO);
            barrier_sync();
        }
    }

    // ---- epilogue ----
    if (LNFUSE == 0) {
        unsigned short* outp = (unsigned short*)dstv;
#pragma unroll
        for (int mi = 0; mi < MF; mi++) {
            size_t rbase = (size_t)row0 + wm * WROWS + mi * 16 + (lane >> 4) * 4;
#pragma unroll
            for (int ni = 0; ni < 4; ni++) {
                int c = wn * 64 + ni * 16 + (lane & 15);
                float bb = bias[c];
                f32x4 v = acc[mi][ni];
#pragma unroll
                for (int r = 0; r < 4; r++) {
                    float t = v[r] + bb;
                    t = (t >= 0.f) ? t : 0.2f * t;
                    outp[(rbase + r) * HH + c] = f2b(t);
                }
            }
        }
    } else {
        float bb[4];
#pragma unroll
        for (int ni = 0; ni < 4; ni++) bb[ni] = bias[wn * 64 + ni * 16 + (lane & 15)];

#pragma unroll
        for (int mi = 0; mi < MF; mi++) {
#pragma unroll
            for (int r = 0; r < 4; r++) {
                float s = 0.f, q = 0.f;
#pragma unroll
                for (int ni = 0; ni < 4; ni++) {
                    float v = acc[mi][ni][r] + bb[ni];
                    s += v; q += v * v;
                }
                s += __shfl_xor(s, 1); q += __shfl_xor(q, 1);
                s += __shfl_xor(s, 2); q += __shfl_xor(q, 2);
                s += __shfl_xor(s, 4); q += __shfl_xor(q, 4);
                s += __shfl_xor(s, 8); q += __shfl_xor(q, 8);
                if ((lane & 15) == 0) {
                    int row = wm * WROWS + mi * 16 + (lane >> 4) * 4 + r;
                    lnred[row][wn]     = s;
                    lnred[row][4 + wn] = q;
                }
            }
        }
        __syncthreads();

        float gv[4], bv[4];
#pragma unroll
        for (int ni = 0; ni < 4; ni++) {
            int c = wn * 64 + ni * 16 + (lane & 15);
            gv[ni] = lng[c]; bv[ni] = lnb[c];
        }

#pragma unroll
        for (int mi = 0; mi < MF; mi++) {
#pragma unroll
            for (int r = 0; r < 4; r++) {
                int row = wm * WROWS + mi * 16 + (lane >> 4) * 4 + r;
                float s = lnred[row][0] + lnred[row][1] + lnred[row][2] + lnred[row][3];
                float q = lnred[row][4] + lnred[row][5] + lnred[row][6] + lnred[row][7];
                float mu  = s * (1.0f / HH);
                float var = q * (1.0f / HH) - mu * mu;
                float inv = rsqrtf(var + 1e-5f);
                size_t grow = (size_t)row0 + row;
#pragma unroll
                for (int ni = 0; ni < 4; ni++) {
                    int c = wn * 64 + ni * 16 + (lane & 15);
                    float v = acc[mi][ni][r] + bb[ni];
                    float y = (v - mu) * inv * gv[ni] + bv[ni];
                    y = (y >= 0.f) ? y : 0.2f * y;
                    if (OUT == 2) {
                        ((float*)dstv)[grow * HH + c] = y;
                    } else {
                        if (OUT == 1) y += b2f(prev[(2 * grow) * HH + c]);
                        ((unsigned short*)dstv)[grow * HH + c] = f2b(y);
                    }
                }
            }
        }
    }
}

// ================= fused up-stage (stages 3/4): conv2(LN(leaky(conv1(up+res)))) in one kernel ====
// conv1: Aeff = A[r] + upsample2(Cc)[r]; out1 = leaky(Aeff @ B1 + b1) -> LDS A2 tile (bf16)
// conv2: out = LN(A2 @ B2 + b2) (leaky) -> dst (bf16). No neighbor mixing in either conv.
template<int BM>
__launch_bounds__(512)
__global__ void up_stage_fused(const unsigned short* __restrict__ A,
                               const unsigned short* __restrict__ Cc,
                               const unsigned short* __restrict__ B1,
                               const float* __restrict__ b1,
                               const unsigned short* __restrict__ B2,
                               const float* __restrict__ b2,
                               const float* __restrict__ lng,
                               const float* __restrict__ lnb,
                               unsigned short* __restrict__ dst,
                               int Tl, int Tc, int tlshift)
{
    constexpr int MF = BM / 32;
    constexpr int WROWS = BM / 2;
    __shared__ unsigned short As[3][BM * 32];
    __shared__ unsigned short Bs[3][256 * 32];
    __shared__ unsigned short A2[BM * 256];
    __shared__ float lnred[BM][8];

    const int tid  = threadIdx.x;
    const int lane = tid & 63;
    const int w    = tid >> 6;
    const int wm   = w & 1, wn = w >> 1;
    const long row0 = (long)blockIdx.x * BM;

    const bool hasA   = (tid < BM * 4);
    const bool hasA_w = (w < (BM * 4) / 64);
    const int arr = tid >> 2;
    const int akk = swz_ks(tid);
    const long gr = row0 + (hasA ? arr : 0);

    // upsample+residual producer precompute
    float ca, cb; size_t rc0, rc1;
    {
        int t = (int)(gr & (long)(Tl - 1));
        long bq = gr >> tlshift;
        int k = t >> 1;
        rc0 = (size_t)bq * Tc + k;
        if (!(t & 1))        { ca = 1.0f; cb = 0.0f; rc1 = rc0; }
        else if (k < Tc - 1) { ca = 0.5f; cb = 0.5f; rc1 = rc0 + 1; }
        else                 { ca = 0.9f; cb = 0.1f; rc1 = rc0 - 1; }
    }

    f32x4 acc[MF][4] = {};
    PVv pvE = {}, pvO = {};

    // ---------------- phase 1: conv1 (AMODE=2, NT=8) ----------------
    auto issueB1 = [&](int t) {
        const int k0 = t * 32;
        const int sl = t % 3;
        gload16(B1 + (size_t)arr * HH + k0 + akk * 8,         &Bs[sl][tid * 8]);
        gload16(B1 + (size_t)(128 + arr) * HH + k0 + akk * 8, &Bs[sl][(tid + 512) * 8]);
    };
    auto issueA1 = [&](int t, PVv& pv) {
        if (!hasA) return;
        const int k0 = t * 32;
        pv.v0 = *(const u16x8*)(A + (size_t)gr * HH + k0 + akk * 8);
        pv.v1 = *(const u16x8*)(Cc + rc0 * HH + k0 + akk * 8);
        pv.v2 = *(const u16x8*)(Cc + rc1 * HH + k0 + akk * 8);
    };
    auto finishA1 = [&](int t, PVv& pv) {
        if (!hasA) return;
        const int sl = t % 3;
        u16x8 o;
#pragma unroll
        for (int j = 0; j < 8; j++)
            o[j] = f2b(b2f(pv.v0[j]) + ca * b2f(pv.v1[j]) + cb * b2f(pv.v2[j]));
        *(u16x8*)&As[sl][tid * 8] = o;
    };
    const int L1 = hasA_w ? 5 : 2;

    issueB1(0); issueA1(0, pvE);
    issueB1(1); issueA1(1, pvO);
    wait_vm(L1);
    finishA1(0, pvE);
    barrier_sync();

#pragma unroll
    for (int t = 0; t < 8; ++t) {
        if (t + 2 < 8) {
            issueB1(t + 2);
            if (((t + 2) & 1) == 0) issueA1(t + 2, pvE); else issueA1(t + 2, pvO);
        }
        const int sl = t % 3;
        __builtin_amdgcn_s_setprio(1);
        short8 af[MF], bg[4];
#pragma unroll
        for (int i = 0; i < MF; i++)
            af[i] = *(const short8*)&As[sl][frag_idx(wm * WROWS + i * 16 + (lane & 15), lane >> 4)];
#pragma unroll
        for (int i = 0; i < 4; i++)
            bg[i] = *(const short8*)&Bs[sl][frag_idx(wn * 64 + i * 16 + (lane & 15), lane >> 4)];
#pragma unroll
        for (int mi = 0; mi < MF; mi++)
#pragma unroll
            for (int ni = 0; ni < 4; ni++)
                acc[mi][ni] = __builtin_amdgcn_mfma_f32_16x16x32_bf16(af[mi], bg[ni], acc[mi][ni], 0, 0, 0);
        __builtin_amdgcn_s_setprio(0);
        if (t + 1 < 8) {
            wait_vm((t + 2 < 8) ? L1 : 0);
            if (((t + 1) & 1) == 0) finishA1(t + 1, pvE); else finishA1(t + 1, pvO);
            barrier_sync();
        }
    }

    // conv1 epilogue: leaky -> A2 tile (bf16)
#pragma unroll
    for (int mi = 0; mi < MF; mi++) {
#pragma unroll
        for (int ni = 0; ni < 4; ni++) {
            int c = wn * 64 + ni * 16 + (lane & 15);
            float bb1 = b1[c];
            int g = c >> 3, e = c & 7;
            f32x4 v = acc[mi][ni];
#pragma unroll
            for (int r = 0; r < 4; r++) {
                int row = wm * WROWS + mi * 16 + (lane >> 4) * 4 + r;
                float t = v[r] + bb1;
                t = (t >= 0.f) ? t : 0.2f * t;
                A2[a2_idx(row, g) + e] = f2b(t);
            }
        }
    }
    __syncthreads();   // A2 complete; all Bs reads of phase 1 done

    // ---------------- phase 2: conv2 (A from A2, NT=8) ----------------
#pragma unroll
    for (int mi = 0; mi < MF; mi++)
#pragma unroll
        for (int ni = 0; ni < 4; ni++)
            acc[mi][ni] = f32x4{};

    auto issueB2 = [&](int t) {
        const int k0 = t * 32;
        const int sl = t % 3;
        gload16(B2 + (size_t)arr * HH + k0 + akk * 8,         &Bs[sl][tid * 8]);
        gload16(B2 + (size_t)(128 + arr) * HH + k0 + akk * 8, &Bs[sl][(tid + 512) * 8]);
    };

    issueB2(0);
    issueB2(1);
    wait_vm(2);
    barrier_sync();

#pragma unroll
    for (int t = 0; t < 8; ++t) {
        if (t + 2 < 8) issueB2(t + 2);
        const int sl = t % 3;
        __builtin_amdgcn_s_setprio(1);
        short8 af[MF], bg[4];
#pragma unroll
        for (int i = 0; i < MF; i++) {
            int row = wm * WROWS + i * 16 + (lane & 15);
            int g = t * 4 + (lane >> 4);
            af[i] = *(const short8*)&A2[a2_idx(row, g)];
        }
#pragma unroll
        for (int i = 0; i < 4; i++)
            bg[i] = *(const short8*)&Bs[sl][frag_idx(wn * 64 + i * 16 + (lane & 15), lane >> 4)];
#pragma unroll
        for (int mi = 0; mi < MF; mi++)
#pragma unroll
            for (int ni = 0; ni < 4; ni++)
                acc[mi][ni] = __builtin_amdgcn_mfma_f32_16x16x32_bf16(af[mi], bg[ni], acc[mi][ni], 0, 0, 0);
        __builtin_amdgcn_s_setprio(0);
        if (t + 1 < 8) {
            wait_vm((t + 2 < 8) ? 2 : 0);
            barrier_sync();
        }
    }

    // ---------------- LN epilogue (bf16 out) ----------------
    float bb[4];
#pragma unroll
    for (int ni = 0; ni < 4; ni++) bb[ni] = b2[wn * 64 + ni * 16 + (lane & 15)];

#pragma unroll
    for (int mi = 0; mi < MF; mi++) {
#pragma unroll
        for (int r = 0; r < 4; r++) {
            float s = 0.f, q = 0.f;
#pragma unroll
            for (int ni = 0; ni < 4; ni++) {
                float v = acc[mi][ni][r] + bb[ni];
                s += v; q += v * v;
            }
            s += __shfl_xor(s, 1); q += __shfl_xor(q, 1);
            s += __shfl_xor(s, 2); q += __shfl_xor(q, 2);
            s += __shfl_xor(s, 4); q += __shfl_xor(q, 4);
            s += __shfl_xor(s, 8); q += __shfl_xor(q, 8);
            if ((lane & 15) == 0) {
                int row = wm * WROWS + mi * 16 + (lane >> 4) * 4 + r;
                lnred[row][wn]     = s;
                lnred[row][4 + wn] = q;
            }
        }
    }
    __syncthreads();

    float gv[4], bv[4];
#pragma unroll
    for (int ni = 0; ni < 4; ni++) {
        int c = wn * 64 + ni * 16 + (lane & 15);
        gv[ni] = lng[c]; bv[ni] = lnb[c];
    }

#pragma unroll
    for (int mi = 0; mi < MF; mi++) {
#pragma unroll
        for (int r = 0; r < 4; r++) {
            int row = wm * WROWS + mi * 16 + (lane >> 4) * 4 + r;
            float s = lnred[row][0] + lnred[row][1] + lnred[row][2] + lnred[row][3];
            float q = lnred[row][4] + lnred[row][5] + lnred[row][6] + lnred[row][7];
            float mu  = s * (1.0f / HH);
            float var = q * (1.0f / HH) - mu * mu;
            float inv = rsqrtf(var + 1e-5f);
            size_t grow = (size_t)row0 + row;
#pragma unroll
            for (int ni = 0; ni < 4; ni++) {
                int c = wn * 64 + ni * 16 + (lane & 15);
                float v = acc[mi][ni][r] + bb[ni];
                float y = (v - mu) * inv * gv[ni] + bv[ni];
                y = (y >= 0.f) ? y : 0.2f * y;
                dst[grow * HH + c] = f2b(y);
            }
        }
    }
}

// ---------------- projection GEMM, same depth-2 pipeline: A fp32 -> bf16 producer -----------------
__launch_bounds__(512)
__global__ void proj_gemm(const float* __restrict__ A, const unsigned short* __restrict__ Bt,
                          const float* __restrict__ bias, unsigned short* __restrict__ out)
{
    constexpr int NT = FDIM / 32;   // 32
    __shared__ unsigned short As[3][128 * 32];
    __shared__ unsigned short Bs[3][256 * 32];
    const int tid  = threadIdx.x;
    const int lane = tid & 63;
    const int w    = tid >> 6;
    const int wm   = w & 1, wn = w >> 1;
    const size_t row0 = (size_t)blockIdx.x * 128;

    const int arr = tid >> 2;
    const int akk = swz_ks(tid);

    f32x4 acc[4][4] = {};
    float4 paE0, paE1, paO0, paO1;

    auto issue = [&](int t, float4& p0, float4& p1) {
        const int k0 = t * 32;
        const int sl = t % 3;
        gload16(Bt + (size_t)arr * FDIM + k0 + akk * 8,         &Bs[sl][tid * 8]);
        gload16(Bt + (size_t)(128 + arr) * FDIM + k0 + akk * 8, &Bs[sl][(tid + 512) * 8]);
        const float* s = A + (row0 + arr) * (size_t)FDIM + k0 + akk * 8;
        p0 = *(const float4*)s;
        p1 = *(const float4*)(s + 4);
    };
    auto finish = [&](int t, float4& p0, float4& p1) {
        const int sl = t % 3;
        u16x8 o = { f2b(p0.x), f2b(p0.y), f2b(p0.z), f2b(p0.w),
                    f2b(p1.x), f2b(p1.y), f2b(p1.z), f2b(p1.w) };
        *(u16x8*)&As[sl][tid * 8] = o;
    };

    issue(0, paE0, paE1);
    issue(1, paO0, paO1);
    wait_vm(4);
    finish(0, paE0, paE1);
    barrier_sync();

#pragma unroll
    for (int t = 0; t < NT; ++t) {
        if (t + 2 < NT) {
            if (((t + 2) & 1) == 0) issue(t + 2, paE0, paE1); else issue(t + 2, paO0, paO1);
        }

        const int sl = t % 3;
        __builtin_amdgcn_s_setprio(1);
        short8 af[4], bg[4];
#pragma unroll
        for (int i = 0; i < 4; i++) {
            af[i] = *(const short8*)&As[sl][frag_idx(wm * 64 + i * 16 + (lane & 15), lane >> 4)];
            bg[i] = *(const short8*)&Bs[sl][frag_idx(wn * 64 + i * 16 + (lane & 15), lane >> 4)];
        }
#pragma unroll
        for (int mi = 0; mi < 4; mi++)
#pragma unroll
            for (int ni = 0; ni < 4; ni++)
                acc[mi][ni] = __builtin_amdgcn_mfma_f32_16x16x32_bf16(af[mi], bg[ni], acc[mi][ni], 0, 0, 0);
        __builtin_amdgcn_s_setprio(0);

        if (t + 1 < NT) {
            wait_vm((t + 2 < NT) ? 4 : 0);
            if (((t + 1) & 1) == 0) finish(t + 1, paE0, paE1); else finish(t + 1, paO0, paO1);
            barrier_sync();
        }
    }

#pragma unroll
    for (int mi = 0; mi < 4; mi++) {
        size_t rbase = row0 + wm * 64 + mi * 16 + (lane >> 4) * 4;
#pragma unroll
        for (int ni = 0; ni < 4; ni++) {
            int c = wn * 64 + ni * 16 + (lane & 15);
            float bb = bias[c];
            f32x4 v = acc[mi][ni];
#pragma unroll
            for (int r = 0; r < 4; r++)
                out[(rbase + r) * HH + c] = f2b(v[r] + bb);
        }
    }
}

// ---------------- upsample + residual add (bf16), in place on res (stage 5 only) ------------------
__global__ void upsample_add_kernel(unsigned short* __restrict__ res, const unsigned short* __restrict__ c,
                                    int Tc, int tlshift, int Rout)
{
    int idx = blockIdx.x * 256 + threadIdx.x;
    int r = idx >> 5, cc = (idx & 31) * 8;
    if (r >= Rout) return;
    int Tl = Tc * 2;
    int t  = r & (Tl - 1);
    int bq = r >> tlshift;
    int k  = t >> 1;
    size_t rc = (size_t)bq * Tc + k;
    float u[8];
    if (!(t & 1)) {
        u16x8 v = *(const u16x8*)(c + rc * HH + cc);
#pragma unroll
        for (int j = 0; j < 8; j++) u[j] = b2f(v[j]);
    } else if (k < Tc - 1) {
        u16x8 v0 = *(const u16x8*)(c + rc * HH + cc);
        u16x8 v1 = *(const u16x8*)(c + (rc + 1) * HH + cc);
#pragma unroll
        for (int j = 0; j < 8; j++) u[j] = 0.5f * (b2f(v0[j]) + b2f(v1[j]));
    } else {
        u16x8 v0 = *(const u16x8*)(c + rc * HH + cc);
        u16x8 vm = *(const u16x8*)(c + (rc - 1) * HH + cc);
#pragma unroll
        for (int j = 0; j < 8; j++) u[j] = 0.9f * b2f(v0[j]) + 0.1f * b2f(vm[j]);
    }
    u16x8 rv = *(const u16x8*)(res + (size_t)r * HH + cc);
    u16x8 o;
#pragma unroll
    for (int j = 0; j < 8; j++) o[j] = f2b(b2f(rv[j]) + u[j]);
    *(u16x8*)(res + (size_t)r * HH + cc) = o;
}

extern "C" void kernel_launch(void* const* d_in, const int* in_sizes, int n_in,
                              void* d_out, int out_size, void* d_ws, size_t ws_size,
                              hipStream_t stream)
{
    const float* x     = (const float*)d_in[0];
    const float* Wp    = (const float*)d_in[6];
    const float* bp    = (const float*)d_in[7];
    const float* Wself = (const float*)d_in[8];
    const float* Wnbr  = (const float*)d_in[9];
    const float* bconv = (const float*)d_in[10];
    const float* ln_g  = (const float*)d_in[11];
    const float* ln_b  = (const float*)d_in[12];
    float* out = (float*)d_out;

    char* p = (char*)d_ws;
    unsigned short* Wself_t = (unsigned short*)p; p += (size_t)12 * HH * HH * 2;
    unsigned short* Wnbr_t  = (unsigned short*)p; p += (size_t)12 * HH * HH * 2;
    unsigned short* Wp_t    = (unsigned short*)p; p += (size_t)HH * FDIM * 2;
    unsigned short* c0 = (unsigned short*)p; p += (size_t)R0 * HH * 2;   // 32 MiB
    unsigned short* c1 = (unsigned short*)p; p += (size_t)R1 * HH * 2;   // 16 MiB
    unsigned short* c2 = (unsigned short*)p; p += (size_t)R2 * HH * 2;   //  8 MiB
    unsigned short* c3 = (unsigned short*)p; p += (size_t)R3 * HH * 2;   //  4 MiB
    unsigned short* t1 = (unsigned short*)p; p += (size_t)R0 * HH * 2;   // 32 MiB
    if (ws_size < (size_t)(p - (char*)d_ws)) return;

    auto Ws = [&](int i) { return Wself_t + (size_t)i * HH * HH; };
    auto Wn = [&](int i) { return Wnbr_t  + (size_t)i * HH * HH; };

    // weight prep (single launch)
    transpose_all<<<1792, 256, 0, stream>>>(Wself, Wnbr, Wp, Wself_t, Wnbr_t, Wp_t);

    // projection: c0 = x @ Wp + bp
    proj_gemm<<<R0 / 128, 512, 0, stream>>>(x, Wp_t, bp, c0);

    // ---- down path (downsample fused into conv1 A-load; residual fused into conv2 LN epilogue) ----
    // stage 0 (R1 = 32768): BM=128 -> 256 blocks
    conv_fused<128, 1, 1, 0, 0><<<R1 / 128, 512, 0, stream>>>(c0, nullptr, nullptr, Ws(0), Wn(0),
        bconv + 0 * HH, nullptr, nullptr, t1, 2048, 0, 0);
    conv_fused<128, 0, 1, 1, 1><<<R1 / 128, 512, 0, stream>>>(t1, nullptr, c0, Ws(1), Wn(1),
        bconv + 1 * HH, ln_g + 0 * HH, ln_b + 0 * HH, c1, 2048, 0, 0);

    // stage 1 (R2 = 16384): BM=64 -> 256 blocks
    conv_fused<64, 1, 1, 0, 0><<<R2 / 64, 512, 0, stream>>>(c1, nullptr, nullptr, Ws(2), Wn(2),
        bconv + 2 * HH, nullptr, nullptr, t1, 1024, 0, 0);
    conv_fused<64, 0, 1, 1, 1><<<R2 / 64, 512, 0, stream>>>(t1, nullptr, c1, Ws(3), Wn(3),
        bconv + 3 * HH, ln_g + 1 * HH, ln_b + 1 * HH, c2, 1024, 0, 0);

    // stage 2 (R3 = 8192): BM=32 -> 256 blocks
    conv_fused<32, 1, 1, 0, 0><<<R3 / 32, 512, 0, stream>>>(c2, nullptr, nullptr, Ws(4), Wn(4),
        bconv + 4 * HH, nullptr, nullptr, t1, 512, 0, 0);
    conv_fused<32, 0, 1, 1, 1><<<R3 / 32, 512, 0, stream>>>(t1, nullptr, c2, Ws(5), Wn(5),
        bconv + 5 * HH, ln_g + 2 * HH, ln_b + 2 * HH, c3, 512, 0, 0);

    // ---- up path ----
    // stage 3 (R2): fused conv1+conv2, BM=64 -> 256 blocks (in-place on c2)
    up_stage_fused<64><<<R2 / 64, 512, 0, stream>>>(c2, c3, Ws(6), bconv + 6 * HH,
        Ws(7), bconv + 7 * HH, ln_g + 3 * HH, ln_b + 3 * HH, c2, 1024, 512, 10);

    // stage 4 (R1): fused conv1+conv2, BM=64 -> 512 blocks (in-place on c1)
    up_stage_fused<64><<<R1 / 64, 512, 0, stream>>>(c1, c2, Ws(8), bconv + 8 * HH,
        Ws(9), bconv + 9 * HH, ln_g + 4 * HH, ln_b + 4 * HH, c1, 2048, 1024, 11);

    // stage 5 (R0): materialized upsample; BM=128 convs (512 blocks)
    upsample_add_kernel<<<R0 / 8, 256, 0, stream>>>(c0, c1, 2048, 12, R0);
    conv_fused<128, 0, 1, 0, 0><<<R0 / 128, 512, 0, stream>>>(c0, nullptr, nullptr, Ws(10), Wn(10),
        bconv + 10 * HH, nullptr, nullptr, t1, 4096, 0, 0);
    conv_fused<128, 0, 1, 1, 2><<<R0 / 128, 512, 0, stream>>>(t1, nullptr, nullptr, Ws(11), Wn(11),
        bconv + 11 * HH, ln_g + 5 * HH, ln_b + 5 * HH, out, 4096, 0, 0);
}

// Round 17
// 347.277 us; speedup vs baseline: 1.1845x; 1.0162x over previous
//
#include <hip/hip_runtime.h>

#define HH 256

typedef __attribute__((ext_vector_type(8))) short short8;
typedef __attribute__((ext_vector_type(4))) float f32x4;
typedef __attribute__((ext_vector_type(4))) unsigned short u16x4;
typedef __attribute__((ext_vector_type(8))) unsigned short u16x8;

constexpr int NBATCH = 16;
constexpr int T0   = 4096;
constexpr int FDIM = 1024;
constexpr int R0   = NBATCH * T0;   // 65536
constexpr int R1   = R0 / 2;        // 32768
constexpr int R2   = R0 / 4;        // 16384
constexpr int R3   = R0 / 8;        // 8192

__device__ __forceinline__ float b2f(unsigned short u) {
    union { unsigned int i; float f; } v; v.i = ((unsigned int)u) << 16; return v.f;
}
__device__ __forceinline__ unsigned short f2b(float f) {
    union { float f; unsigned int i; } v; v.f = f;
    unsigned int r = v.i + 0x7fffu + ((v.i >> 16) & 1u);
    return (unsigned short)(r >> 16);
}
__device__ __forceinline__ void gload16(const void* g, void* l) {
    __builtin_amdgcn_global_load_lds((const __attribute__((address_space(1))) void*)g,
                                     (__attribute__((address_space(3))) void*)l, 16, 0, 0);
}
// raw barrier: drain LDS ops, then s_barrier (no vmcnt drain -- that's the point)
__device__ __forceinline__ void barrier_sync() {
    asm volatile("s_waitcnt lgkmcnt(0)\n\ts_barrier" ::: "memory");
}
// counted vmem wait; n folds to a constant under full unroll
__device__ __forceinline__ void wait_vm(int n) {
    switch (n) {
    case 2:  asm volatile("s_waitcnt vmcnt(2)"  ::: "memory"); break;
    case 3:  asm volatile("s_waitcnt vmcnt(3)"  ::: "memory"); break;
    case 4:  asm volatile("s_waitcnt vmcnt(4)"  ::: "memory"); break;
    case 5:  asm volatile("s_waitcnt vmcnt(5)"  ::: "memory"); break;
    case 6:  asm volatile("s_waitcnt vmcnt(6)"  ::: "memory"); break;
    default: asm volatile("s_waitcnt vmcnt(0)"  ::: "memory"); break;
    }
}
// LDS slot swizzle: slot s (16B granules) holds k-group ks = (s&3) ^ ((s>>3)&3) of row s>>2.
__device__ __forceinline__ int swz_ks(int chunk)        { return (chunk & 3) ^ ((chunk >> 3) & 3); }
__device__ __forceinline__ int frag_idx(int row, int g) { return (row * 4 + (g ^ ((row >> 1) & 3))) * 8; }
// A2 tile (fused up-stage): [row][256] bf16, granule swizzle g^(row&31); elem index
__device__ __forceinline__ int a2_idx(int row, int g)   { return (row * 32 + (g ^ (row & 31))) * 8; }

struct PVv { u16x8 v0, v1, v2, v3; };

// ---------------- weight transpose+convert (merged): fp32 [K][256] -> bf16 [256][K] --------------
__device__ __forceinline__ void transpose_tile(const float* __restrict__ src,
                                               unsigned short* __restrict__ dst,
                                               int K, int tilesPerMat, int bid, int tidx)
{
    int m = bid / tilesPerMat;
    int t = bid % tilesPerMat;
    int tr = t >> 3, tc = t & 7;
    const float* S = src + (size_t)m * K * HH;
    unsigned short* D = dst + (size_t)m * HH * K;
    __shared__ float tile[32][33];
    int x = tidx & 31, y = tidx >> 5;
#pragma unroll
    for (int i = y; i < 32; i += 8)
        tile[i][x] = S[(size_t)(tr * 32 + i) * HH + tc * 32 + x];
    __syncthreads();
#pragma unroll
    for (int i = y; i < 32; i += 8)
        D[(size_t)(tc * 32 + i) * K + tr * 32 + x] = f2b(tile[x][i]);
}

__global__ void transpose_all(const float* __restrict__ Wself, const float* __restrict__ Wnbr,
                              const float* __restrict__ Wp,
                              unsigned short* __restrict__ Ws_t, unsigned short* __restrict__ Wn_t,
                              unsigned short* __restrict__ Wp_t)
{
    int bid = blockIdx.x;
    if (bid < 768)       transpose_tile(Wself, Ws_t, HH,   64,  bid,        threadIdx.x);
    else if (bid < 1536) transpose_tile(Wnbr,  Wn_t, HH,   64,  bid - 768,  threadIdx.x);
    else                 transpose_tile(Wp,    Wp_t, FDIM, 256, bid - 1536, threadIdx.x);
}

// ================= unified conv GEMM, depth-2 counted-vmcnt pipeline (BM = 32 / 64 / 128) ========
// out = Aeff @ Bself [+ nbrmean(Aeff) @ Bnbr] + bias, then leaky (LNFUSE=0) or LN+leaky (LNFUSE=1).
// AMODE 0: Aeff=A[r]  1: A[2r] (fused downsample)  2: A[r]+upsample2(Cc)[r] (fused up+residual)
// OUT (LNFUSE=1 only) 0: bf16  1: bf16 + prev[2r] residual  2: fp32 final
template<int BM, int AMODE, int NBR, int LNFUSE, int OUT>
__launch_bounds__(512)
__global__ void conv_fused(const unsigned short* __restrict__ A,
                           const unsigned short* __restrict__ Cc,
                           const unsigned short* __restrict__ prev,
                           const unsigned short* __restrict__ Bself,
                           const unsigned short* __restrict__ Bnbr,
                           const float* __restrict__ bias,
                           const float* __restrict__ lng,
                           const float* __restrict__ lnb,
                           void* __restrict__ dstv,
                           int Tl, int Tc, int tlshift)
{
    constexpr int NT = NBR ? 16 : 8;
    constexpr int MF = (BM + 31) / 32;   // m-frags per wave (BM=32 -> 1)
    constexpr int WROWS = BM / 2;        // rows per wave-m half
    __shared__ unsigned short As[3][BM * 32];
    __shared__ unsigned short Bs[3][256 * 32];
    __shared__ float lnred[LNFUSE ? BM : 1][8];

    const int tid  = threadIdx.x;
    const int lane = tid & 63;
    const int w    = tid >> 6;
    const int wm   = w & 1, wn = w >> 1;
    const long row0 = (long)blockIdx.x * BM;

    const bool hasA   = (tid < BM * 4);       // threads that stage A
    const bool hasA_w = (w < (BM * 4) / 64);  // wave-uniform version (for vmcnt counts)
    const int arr = tid >> 2;                 // staging row
    const int akk = swz_ks(tid);
    const long gr = row0 + (hasA ? arr : 0);

    // ---- producer precompute ----
    float ca = 0.f, cb = 0.f; size_t rc0 = 0, rc1 = 0;
    if (AMODE == 2) {
        int t = (int)(gr & (long)(Tl - 1));
        long bq = gr >> tlshift;
        int k = t >> 1;
        rc0 = (size_t)bq * Tc + k;
        if (!(t & 1))        { ca = 1.0f; cb = 0.0f; rc1 = rc0; }
        else if (k < Tc - 1) { ca = 0.5f; cb = 0.5f; rc1 = rc0 + 1; }
        else                 { ca = 0.9f; cb = 0.1f; rc1 = rc0 - 1; }
    }
    float vinv = 1.f;
    float cf0 = 0.f, cf1 = 0.f, cf2 = 0.f, cf3 = 0.f;
    size_t nrow0 = 0, nrow1 = 0, nrow2 = 0, nrow3 = 0;
    if (NBR) {
        const int offs[4] = {-2, -1, 1, 2};
        int t = (int)(gr & (long)(Tl - 1));
        int cnt = 0;
        float cf[4]; size_t nr[4];
#pragma unroll
        for (int oi = 0; oi < 4; oi++) {
            int tn = t + offs[oi];
            bool v = (tn >= 0 && tn < Tl);
            cnt += v ? 1 : 0;
            int tcl = tn < 0 ? 0 : (tn > Tl - 1 ? Tl - 1 : tn);
            long r = gr - t + tcl;
            nr[oi] = (size_t)((AMODE == 1) ? 2 * r : r) * HH;
            cf[oi] = v ? 1.f : 0.f;
        }
        vinv = 1.f / (float)cnt;
        cf0 = cf[0]; cf1 = cf[1]; cf2 = cf[2]; cf3 = cf[3];
        nrow0 = nr[0]; nrow1 = nr[1]; nrow2 = nr[2]; nrow3 = nr[3];
    }

    f32x4 acc[MF][4] = {};
    PVv pvE = {}, pvO = {};

    auto Lof = [&](int t) -> int {
        if (!hasA_w) return 2;
        const int seg = (NBR && t >= 8) ? 1 : 0;
        return seg ? 6 : (AMODE == 2 ? 5 : 3);
    };
    auto issueB = [&](int t) {
        const int seg = (NBR && t >= 8) ? 1 : 0;
        const int k0 = (t & 7) * 32;
        const int sl = t % 3;
        const unsigned short* __restrict__ Bm = seg ? Bnbr : Bself;
        gload16(Bm + (size_t)arr * HH + k0 + akk * 8,         &Bs[sl][tid * 8]);
        gload16(Bm + (size_t)(128 + arr) * HH + k0 + akk * 8, &Bs[sl][(tid + 512) * 8]);
    };
    auto issueA = [&](int t, PVv& pv) {
        if (!hasA) return;
        const int seg = (NBR && t >= 8) ? 1 : 0;
        const int k0 = (t & 7) * 32;
        const int sl = t % 3;
        if (seg == 0) {
            if (AMODE == 0) {
                gload16(A + (size_t)gr * HH + k0 + akk * 8, &As[sl][tid * 8]);
            } else if (AMODE == 1) {
                gload16(A + (size_t)(2 * gr) * HH + k0 + akk * 8, &As[sl][tid * 8]);
            } else {
                pv.v0 = *(const u16x8*)(A + (size_t)gr * HH + k0 + akk * 8);
                pv.v1 = *(const u16x8*)(Cc + rc0 * HH + k0 + akk * 8);
                pv.v2 = *(const u16x8*)(Cc + rc1 * HH + k0 + akk * 8);
            }
        } else {
            pv.v0 = *(const u16x8*)(A + nrow0 + k0 + akk * 8);
            pv.v1 = *(const u16x8*)(A + nrow1 + k0 + akk * 8);
            pv.v2 = *(const u16x8*)(A + nrow2 + k0 + akk * 8);
            pv.v3 = *(const u16x8*)(A + nrow3 + k0 + akk * 8);
        }
    };
    auto finishA = [&](int t, PVv& pv) {
        if (!hasA) return;
        const int seg = (NBR && t >= 8) ? 1 : 0;
        const int sl = t % 3;
        if (seg == 0) {
            if (AMODE == 2) {
                u16x8 o;
#pragma unroll
                for (int j = 0; j < 8; j++)
                    o[j] = f2b(b2f(pv.v0[j]) + ca * b2f(pv.v1[j]) + cb * b2f(pv.v2[j]));
                *(u16x8*)&As[sl][tid * 8] = o;
            }
        } else {
            u16x8 o;
#pragma unroll
            for (int j = 0; j < 8; j++) {
                float a = cf0 * b2f(pv.v0[j]) + cf1 * b2f(pv.v1[j])
                        + cf2 * b2f(pv.v2[j]) + cf3 * b2f(pv.v3[j]);
                o[j] = f2b(a * vinv);
            }
            *(u16x8*)&As[sl][tid * 8] = o;
        }
    };

    issueB(0); issueA(0, pvE);
    issueB(1); issueA(1, pvO);
    wait_vm(Lof(1));
    finishA(0, pvE);
    barrier_sync();

#pragma unroll
    for (int t = 0; t < NT; ++t) {
        if (t + 2 < NT) {
            issueB(t + 2);
            if (((t + 2) & 1) == 0) issueA(t + 2, pvE); else issueA(t + 2, pvO);
        }

        const int sl = t % 3;
        __builtin_amdgcn_s_setprio(1);
        short8 af[MF], bg[4];
#pragma unroll
        for (int i = 0; i < MF; i++)
            af[i] = *(const short8*)&As[sl][frag_idx(wm * WROWS + i * 16 + (lane & 15), lane >> 4)];
#pragma unroll
        for (int i = 0; i < 4; i++)
            bg[i] = *(const short8*)&Bs[sl][frag_idx(wn * 64 + i * 16 + (lane & 15), lane >> 4)];
#pragma unroll
        for (int mi = 0; mi < MF; mi++)
#pragma unroll
            for (int ni = 0; ni < 4; ni++)
                acc[mi][ni] = __builtin_amdgcn_mfma_f32_16x16x32_bf16(af[mi], bg[ni], acc[mi][ni], 0, 0, 0);
        __builtin_amdgcn_s_setprio(0);

        if (t + 1 < NT) {
            wait_vm((t + 2 < NT) ? Lof(t + 2) : 0);
            if (((t + 1) & 1) == 0) finishA(t + 1, pvE); else finishA(t + 1, pvO);
            barrier_sync();
        }
    }

    // ---- epilogue ----
    if (LNFUSE == 0) {
        unsigned short* outp = (unsigned short*)dstv;
#pragma unroll
        for (int mi = 0; mi < MF; mi++) {
            size_t rbase = (size_t)row0 + wm * WROWS + mi * 16 + (lane >> 4) * 4;
#pragma unroll
            for (int ni = 0; ni < 4; ni++) {
                int c = wn * 64 + ni * 16 + (lane & 15);
                float bb = bias[c];
                f32x4 v = acc[mi][ni];
#pragma unroll
                for (int r = 0; r < 4; r++) {
                    float t = v[r] + bb;
                    t = (t >= 0.f) ? t : 0.2f * t;
                    outp[(rbase + r) * HH + c] = f2b(t);
                }
            }
        }
    } else {
        float bb[4];
#pragma unroll
        for (int ni = 0; ni < 4; ni++) bb[ni] = bias[wn * 64 + ni * 16 + (lane & 15)];

#pragma unroll
        for (int mi = 0; mi < MF; mi++) {
#pragma unroll
            for (int r = 0; r < 4; r++) {
                float s = 0.f, q = 0.f;
#pragma unroll
                for (int ni = 0; ni < 4; ni++) {
                    float v = acc[mi][ni][r] + bb[ni];
                    s += v; q += v * v;
                }
                s += __shfl_xor(s, 1); q += __shfl_xor(q, 1);
                s += __shfl_xor(s, 2); q += __shfl_xor(q, 2);
                s += __shfl_xor(s, 4); q += __shfl_xor(q, 4);
                s += __shfl_xor(s, 8); q += __shfl_xor(q, 8);
                if ((lane & 15) == 0) {
                    int row = wm * WROWS + mi * 16 + (lane >> 4) * 4 + r;
                    lnred[row][wn]     = s;
                    lnred[row][4 + wn] = q;
                }
            }
        }
        __syncthreads();

        float gv[4], bv[4];
#pragma unroll
        for (int ni = 0; ni < 4; ni++) {
            int c = wn * 64 + ni * 16 + (lane & 15);
            gv[ni] = lng[c]; bv[ni] = lnb[c];
        }

#pragma unroll
        for (int mi = 0; mi < MF; mi++) {
#pragma unroll
            for (int r = 0; r < 4; r++) {
                int row = wm * WROWS + mi * 16 + (lane >> 4) * 4 + r;
                float s = lnred[row][0] + lnred[row][1] + lnred[row][2] + lnred[row][3];
                float q = lnred[row][4] + lnred[row][5] + lnred[row][6] + lnred[row][7];
                float mu  = s * (1.0f / HH);
                float var = q * (1.0f / HH) - mu * mu;
                float inv = rsqrtf(var + 1e-5f);
                size_t grow = (size_t)row0 + row;
#pragma unroll
                for (int ni = 0; ni < 4; ni++) {
                    int c = wn * 64 + ni * 16 + (lane & 15);
                    float v = acc[mi][ni][r] + bb[ni];
                    float y = (v - mu) * inv * gv[ni] + bv[ni];
                    y = (y >= 0.f) ? y : 0.2f * y;
                    if (OUT == 2) {
                        ((float*)dstv)[grow * HH + c] = y;
                    } else {
                        if (OUT == 1) y += b2f(prev[(2 * grow) * HH + c]);
                        ((unsigned short*)dstv)[grow * HH + c] = f2b(y);
                    }
                }
            }
        }
    }
}

// ================= fused up-stage (stages 3/4): conv2(LN(leaky(conv1(up+res)))) in one kernel ====
// conv1: Aeff = A[r] + upsample2(Cc)[r]; out1 = leaky(Aeff @ B1 + b1) -> LDS A2 tile (bf16)
// conv2: out = LN(A2 @ B2 + b2) (leaky) -> dst (bf16). No neighbor mixing in either conv.
template<int BM>
__launch_bounds__(512)
__global__ void up_stage_fused(const unsigned short* __restrict__ A,
                               const unsigned short* __restrict__ Cc,
                               const unsigned short* __restrict__ B1,
                               const float* __restrict__ b1,
                               const unsigned short* __restrict__ B2,
                               const float* __restrict__ b2,
                               const float* __restrict__ lng,
                               const float* __restrict__ lnb,
                               unsigned short* __restrict__ dst,
                               int Tl, int Tc, int tlshift)
{
    constexpr int MF = BM / 32;
    constexpr int WROWS = BM / 2;
    __shared__ unsigned short As[3][BM * 32];
    __shared__ unsigned short Bs[3][256 * 32];
    __shared__ unsigned short A2[BM * 256];
    __shared__ float lnred[BM][8];

    const int tid  = threadIdx.x;
    const int lane = tid & 63;
    const int w    = tid >> 6;
    const int wm   = w & 1, wn = w >> 1;
    const long row0 = (long)blockIdx.x * BM;

    const bool hasA   = (tid < BM * 4);
    const bool hasA_w = (w < (BM * 4) / 64);
    const int arr = tid >> 2;
    const int akk = swz_ks(tid);
    const long gr = row0 + (hasA ? arr : 0);

    // upsample+residual producer precompute
    float ca, cb; size_t rc0, rc1;
    {
        int t = (int)(gr & (long)(Tl - 1));
        long bq = gr >> tlshift;
        int k = t >> 1;
        rc0 = (size_t)bq * Tc + k;
        if (!(t & 1))        { ca = 1.0f; cb = 0.0f; rc1 = rc0; }
        else if (k < Tc - 1) { ca = 0.5f; cb = 0.5f; rc1 = rc0 + 1; }
        else                 { ca = 0.9f; cb = 0.1f; rc1 = rc0 - 1; }
    }

    f32x4 acc[MF][4] = {};
    PVv pvE = {}, pvO = {};

    // ---------------- phase 1: conv1 (AMODE=2, NT=8) ----------------
    auto issueB1 = [&](int t) {
        const int k0 = t * 32;
        const int sl = t % 3;
        gload16(B1 + (size_t)arr * HH + k0 + akk * 8,         &Bs[sl][tid * 8]);
        gload16(B1 + (size_t)(128 + arr) * HH + k0 + akk * 8, &Bs[sl][(tid + 512) * 8]);
    };
    auto issueA1 = [&](int t, PVv& pv) {
        if (!hasA) return;
        const int k0 = t * 32;
        pv.v0 = *(const u16x8*)(A + (size_t)gr * HH + k0 + akk * 8);
        pv.v1 = *(const u16x8*)(Cc + rc0 * HH + k0 + akk * 8);
        pv.v2 = *(const u16x8*)(Cc + rc1 * HH + k0 + akk * 8);
    };
    auto finishA1 = [&](int t, PVv& pv) {
        if (!hasA) return;
        const int sl = t % 3;
        u16x8 o;
#pragma unroll
        for (int j = 0; j < 8; j++)
            o[j] = f2b(b2f(pv.v0[j]) + ca * b2f(pv.v1[j]) + cb * b2f(pv.v2[j]));
        *(u16x8*)&As[sl][tid * 8] = o;
    };
    const int L1 = hasA_w ? 5 : 2;

    issueB1(0); issueA1(0, pvE);
    issueB1(1); issueA1(1, pvO);
    wait_vm(L1);
    finishA1(0, pvE);
    barrier_sync();

#pragma unroll
    for (int t = 0; t < 8; ++t) {
        if (t + 2 < 8) {
            issueB1(t + 2);
            if (((t + 2) & 1) == 0) issueA1(t + 2, pvE); else issueA1(t + 2, pvO);
        }
        const int sl = t % 3;
        __builtin_amdgcn_s_setprio(1);
        short8 af[MF], bg[4];
#pragma unroll
        for (int i = 0; i < MF; i++)
            af[i] = *(const short8*)&As[sl][frag_idx(wm * WROWS + i * 16 + (lane & 15), lane >> 4)];
#pragma unroll
        for (int i = 0; i < 4; i++)
            bg[i] = *(const short8*)&Bs[sl][frag_idx(wn * 64 + i * 16 + (lane & 15), lane >> 4)];
#pragma unroll
        for (int mi = 0; mi < MF; mi++)
#pragma unroll
            for (int ni = 0; ni < 4; ni++)
                acc[mi][ni] = __builtin_amdgcn_mfma_f32_16x16x32_bf16(af[mi], bg[ni], acc[mi][ni], 0, 0, 0);
        __builtin_amdgcn_s_setprio(0);
        if (t + 1 < 8) {
            wait_vm((t + 2 < 8) ? L1 : 0);
            if (((t + 1) & 1) == 0) finishA1(t + 1, pvE); else finishA1(t + 1, pvO);
            barrier_sync();
        }
    }

    // conv1 epilogue: leaky -> A2 tile (bf16)
#pragma unroll
    for (int mi = 0; mi < MF; mi++) {
#pragma unroll
        for (int ni = 0; ni < 4; ni++) {
            int c = wn * 64 + ni * 16 + (lane & 15);
            float bb1 = b1[c];
            int g = c >> 3, e = c & 7;
            f32x4 v = acc[mi][ni];
#pragma unroll
            for (int r = 0; r < 4; r++) {
                int row = wm * WROWS + mi * 16 + (lane >> 4) * 4 + r;
                float t = v[r] + bb1;
                t = (t >= 0.f) ? t : 0.2f * t;
                A2[a2_idx(row, g) + e] = f2b(t);
            }
        }
    }
    __syncthreads();   // A2 complete; all Bs reads of phase 1 done

    // ---------------- phase 2: conv2 (A from A2, NT=8) ----------------
#pragma unroll
    for (int mi = 0; mi < MF; mi++)
#pragma unroll
        for (int ni = 0; ni < 4; ni++)
            acc[mi][ni] = f32x4{};

    auto issueB2 = [&](int t) {
        const int k0 = t * 32;
        const int sl = t % 3;
        gload16(B2 + (size_t)arr * HH + k0 + akk * 8,         &Bs[sl][tid * 8]);
        gload16(B2 + (size_t)(128 + arr) * HH + k0 + akk * 8, &Bs[sl][(tid + 512) * 8]);
    };

    issueB2(0);
    issueB2(1);
    wait_vm(2);
    barrier_sync();

#pragma unroll
    for (int t = 0; t < 8; ++t) {
        if (t + 2 < 8) issueB2(t + 2);
        const int sl = t % 3;
        __builtin_amdgcn_s_setprio(1);
        short8 af[MF], bg[4];
#pragma unroll
        for (int i = 0; i < MF; i++) {
            int row = wm * WROWS + i * 16 + (lane & 15);
            int g = t * 4 + (lane >> 4);
            af[i] = *(const short8*)&A2[a2_idx(row, g)];
        }
#pragma unroll
        for (int i = 0; i < 4; i++)
            bg[i] = *(const short8*)&Bs[sl][frag_idx(wn * 64 + i * 16 + (lane & 15), lane >> 4)];
#pragma unroll
        for (int mi = 0; mi < MF; mi++)
#pragma unroll
            for (int ni = 0; ni < 4; ni++)
                acc[mi][ni] = __builtin_amdgcn_mfma_f32_16x16x32_bf16(af[mi], bg[ni], acc[mi][ni], 0, 0, 0);
        __builtin_amdgcn_s_setprio(0);
        if (t + 1 < 8) {
            wait_vm((t + 2 < 8) ? 2 : 0);
            barrier_sync();
        }
    }

    // ---------------- LN epilogue (bf16 out) ----------------
    float bb[4];
#pragma unroll
    for (int ni = 0; ni < 4; ni++) bb[ni] = b2[wn * 64 + ni * 16 + (lane & 15)];

#pragma unroll
    for (int mi = 0; mi < MF; mi++) {
#pragma unroll
        for (int r = 0; r < 4; r++) {
            float s = 0.f, q = 0.f;
#pragma unroll
            for (int ni = 0; ni < 4; ni++) {
                float v = acc[mi][ni][r] + bb[ni];
                s += v; q += v * v;
            }
            s += __shfl_xor(s, 1); q += __shfl_xor(q, 1);
            s += __shfl_xor(s, 2); q += __shfl_xor(q, 2);
            s += __shfl_xor(s, 4); q += __shfl_xor(q, 4);
            s += __shfl_xor(s, 8); q += __shfl_xor(q, 8);
            if ((lane & 15) == 0) {
                int row = wm * WROWS + mi * 16 + (lane >> 4) * 4 + r;
                lnred[row][wn]     = s;
                lnred[row][4 + wn] = q;
            }
        }
    }
    __syncthreads();

    float gv[4], bv[4];
#pragma unroll
    for (int ni = 0; ni < 4; ni++) {
        int c = wn * 64 + ni * 16 + (lane & 15);
        gv[ni] = lng[c]; bv[ni] = lnb[c];
    }

#pragma unroll
    for (int mi = 0; mi < MF; mi++) {
#pragma unroll
        for (int r = 0; r < 4; r++) {
            int row = wm * WROWS + mi * 16 + (lane >> 4) * 4 + r;
            float s = lnred[row][0] + lnred[row][1] + lnred[row][2] + lnred[row][3];
            float q = lnred[row][4] + lnred[row][5] + lnred[row][6] + lnred[row][7];
            float mu  = s * (1.0f / HH);
            float var = q * (1.0f / HH) - mu * mu;
            float inv = rsqrtf(var + 1e-5f);
            size_t grow = (size_t)row0 + row;
#pragma unroll
            for (int ni = 0; ni < 4; ni++) {
                int c = wn * 64 + ni * 16 + (lane & 15);
                float v = acc[mi][ni][r] + bb[ni];
                float y = (v - mu) * inv * gv[ni] + bv[ni];
                y = (y >= 0.f) ? y : 0.2f * y;
                dst[grow * HH + c] = f2b(y);
            }
        }
    }
}

// ---------------- projection GEMM, same depth-2 pipeline: A fp32 -> bf16 producer -----------------
__launch_bounds__(512)
__global__ void proj_gemm(const float* __restrict__ A, const unsigned short* __restrict__ Bt,
                          const float* __restrict__ bias, unsigned short* __restrict__ out)
{
    constexpr int NT = FDIM / 32;   // 32
    __shared__ unsigned short As[3][128 * 32];
    __shared__ unsigned short Bs[3][256 * 32];
    const int tid  = threadIdx.x;
    const int lane = tid & 63;
    const int w    = tid >> 6;
    const int wm   = w & 1, wn = w >> 1;
    const size_t row0 = (size_t)blockIdx.x * 128;

    const int arr = tid >> 2;
    const int akk = swz_ks(tid);

    f32x4 acc[4][4] = {};
    float4 paE0, paE1, paO0, paO1;

    auto issue = [&](int t, float4& p0, float4& p1) {
        const int k0 = t * 32;
        const int sl = t % 3;
        gload16(Bt + (size_t)arr * FDIM + k0 + akk * 8,         &Bs[sl][tid * 8]);
        gload16(Bt + (size_t)(128 + arr) * FDIM + k0 + akk * 8, &Bs[sl][(tid + 512) * 8]);
        const float* s = A + (row0 + arr) * (size_t)FDIM + k0 + akk * 8;
        p0 = *(const float4*)s;
        p1 = *(const float4*)(s + 4);
    };
    auto finish = [&](int t, float4& p0, float4& p1) {
        const int sl = t % 3;
        u16x8 o = { f2b(p0.x), f2b(p0.y), f2b(p0.z), f2b(p0.w),
                    f2b(p1.x), f2b(p1.y), f2b(p1.z), f2b(p1.w) };
        *(u16x8*)&As[sl][tid * 8] = o;
    };

    issue(0, paE0, paE1);
    issue(1, paO0, paO1);
    wait_vm(4);
    finish(0, paE0, paE1);
    barrier_sync();

#pragma unroll
    for (int t = 0; t < NT; ++t) {
        if (t + 2 < NT) {
            if (((t + 2) & 1) == 0) issue(t + 2, paE0, paE1); else issue(t + 2, paO0, paO1);
        }

        const int sl = t % 3;
        __builtin_amdgcn_s_setprio(1);
        short8 af[4], bg[4];
#pragma unroll
        for (int i = 0; i < 4; i++) {
            af[i] = *(const short8*)&As[sl][frag_idx(wm * 64 + i * 16 + (lane & 15), lane >> 4)];
            bg[i] = *(const short8*)&Bs[sl][frag_idx(wn * 64 + i * 16 + (lane & 15), lane >> 4)];
        }
#pragma unroll
        for (int mi = 0; mi < 4; mi++)
#pragma unroll
            for (int ni = 0; ni < 4; ni++)
                acc[mi][ni] = __builtin_amdgcn_mfma_f32_16x16x32_bf16(af[mi], bg[ni], acc[mi][ni], 0, 0, 0);
        __builtin_amdgcn_s_setprio(0);

        if (t + 1 < NT) {
            wait_vm((t + 2 < NT) ? 4 : 0);
            if (((t + 1) & 1) == 0) finish(t + 1, paE0, paE1); else finish(t + 1, paO0, paO1);
            barrier_sync();
        }
    }

#pragma unroll
    for (int mi = 0; mi < 4; mi++) {
        size_t rbase = row0 + wm * 64 + mi * 16 + (lane >> 4) * 4;
#pragma unroll
        for (int ni = 0; ni < 4; ni++) {
            int c = wn * 64 + ni * 16 + (lane & 15);
            float bb = bias[c];
            f32x4 v = acc[mi][ni];
#pragma unroll
            for (int r = 0; r < 4; r++)
                out[(rbase + r) * HH + c] = f2b(v[r] + bb);
        }
    }
}

// ---------------- upsample + residual add (bf16), in place on res (stage 5 only) ------------------
__global__ void upsample_add_kernel(unsigned short* __restrict__ res, const unsigned short* __restrict__ c,
                                    int Tc, int tlshift, int Rout)
{
    int idx = blockIdx.x * 256 + threadIdx.x;
    int r = idx >> 5, cc = (idx & 31) * 8;
    if (r >= Rout) return;
    int Tl = Tc * 2;
    int t  = r & (Tl - 1);
    int bq = r >> tlshift;
    int k  = t >> 1;
    size_t rc = (size_t)bq * Tc + k;
    float u[8];
    if (!(t & 1)) {
        u16x8 v = *(const u16x8*)(c + rc * HH + cc);
#pragma unroll
        for (int j = 0; j < 8; j++) u[j] = b2f(v[j]);
    } else if (k < Tc - 1) {
        u16x8 v0 = *(const u16x8*)(c + rc * HH + cc);
        u16x8 v1 = *(const u16x8*)(c + (rc + 1) * HH + cc);
#pragma unroll
        for (int j = 0; j < 8; j++) u[j] = 0.5f * (b2f(v0[j]) + b2f(v1[j]));
    } else {
        u16x8 v0 = *(const u16x8*)(c + rc * HH + cc);
        u16x8 vm = *(const u16x8*)(c + (rc - 1) * HH + cc);
#pragma unroll
        for (int j = 0; j < 8; j++) u[j] = 0.9f * b2f(v0[j]) + 0.1f * b2f(vm[j]);
    }
    u16x8 rv = *(const u16x8*)(res + (size_t)r * HH + cc);
    u16x8 o;
#pragma unroll
    for (int j = 0; j < 8; j++) o[j] = f2b(b2f(rv[j]) + u[j]);
    *(u16x8*)(res + (size_t)r * HH + cc) = o;
}

extern "C" void kernel_launch(void* const* d_in, const int* in_sizes, int n_in,
                              void* d_out, int out_size, void* d_ws, size_t ws_size,
                              hipStream_t stream)
{
    const float* x     = (const float*)d_in[0];
    const float* Wp    = (const float*)d_in[6];
    const float* bp    = (const float*)d_in[7];
    const float* Wself = (const float*)d_in[8];
    const float* Wnbr  = (const float*)d_in[9];
    const float* bconv = (const float*)d_in[10];
    const float* ln_g  = (const float*)d_in[11];
    const float* ln_b  = (const float*)d_in[12];
    float* out = (float*)d_out;

    char* p = (char*)d_ws;
    unsigned short* Wself_t = (unsigned short*)p; p += (size_t)12 * HH * HH * 2;
    unsigned short* Wnbr_t  = (unsigned short*)p; p += (size_t)12 * HH * HH * 2;
    unsigned short* Wp_t    = (unsigned short*)p; p += (size_t)HH * FDIM * 2;
    unsigned short* c0 = (unsigned short*)p; p += (size_t)R0 * HH * 2;   // 32 MiB
    unsigned short* c1 = (unsigned short*)p; p += (size_t)R1 * HH * 2;   // 16 MiB
    unsigned short* c2 = (unsigned short*)p; p += (size_t)R2 * HH * 2;   //  8 MiB
    unsigned short* c3 = (unsigned short*)p; p += (size_t)R3 * HH * 2;   //  4 MiB
    unsigned short* t1 = (unsigned short*)p; p += (size_t)R0 * HH * 2;   // 32 MiB
    if (ws_size < (size_t)(p - (char*)d_ws)) return;

    auto Ws = [&](int i) { return Wself_t + (size_t)i * HH * HH; };
    auto Wn = [&](int i) { return Wnbr_t  + (size_t)i * HH * HH; };

    // weight prep (single launch)
    transpose_all<<<1792, 256, 0, stream>>>(Wself, Wnbr, Wp, Wself_t, Wnbr_t, Wp_t);

    // projection: c0 = x @ Wp + bp
    proj_gemm<<<R0 / 128, 512, 0, stream>>>(x, Wp_t, bp, c0);

    // ---- down path (downsample fused into conv1 A-load; residual fused into conv2 LN epilogue) ----
    // stage 0 (R1 = 32768): BM=128 -> 256 blocks
    conv_fused<128, 1, 1, 0, 0><<<R1 / 128, 512, 0, stream>>>(c0, nullptr, nullptr, Ws(0), Wn(0),
        bconv + 0 * HH, nullptr, nullptr, t1, 2048, 0, 0);
    conv_fused<128, 0, 1, 1, 1><<<R1 / 128, 512, 0, stream>>>(t1, nullptr, c0, Ws(1), Wn(1),
        bconv + 1 * HH, ln_g + 0 * HH, ln_b + 0 * HH, c1, 2048, 0, 0);

    // stage 1 (R2 = 16384): BM=64 -> 256 blocks
    conv_fused<64, 1, 1, 0, 0><<<R2 / 64, 512, 0, stream>>>(c1, nullptr, nullptr, Ws(2), Wn(2),
        bconv + 2 * HH, nullptr, nullptr, t1, 1024, 0, 0);
    conv_fused<64, 0, 1, 1, 1><<<R2 / 64, 512, 0, stream>>>(t1, nullptr, c1, Ws(3), Wn(3),
        bconv + 3 * HH, ln_g + 1 * HH, ln_b + 1 * HH, c2, 1024, 0, 0);

    // stage 2 (R3 = 8192): BM=32 -> 256 blocks
    conv_fused<32, 1, 1, 0, 0><<<R3 / 32, 512, 0, stream>>>(c2, nullptr, nullptr, Ws(4), Wn(4),
        bconv + 4 * HH, nullptr, nullptr, t1, 512, 0, 0);
    conv_fused<32, 0, 1, 1, 1><<<R3 / 32, 512, 0, stream>>>(t1, nullptr, c2, Ws(5), Wn(5),
        bconv + 5 * HH, ln_g + 2 * HH, ln_b + 2 * HH, c3, 512, 0, 0);

    // ---- up path ----
    // stage 3 (R2): fused conv1+conv2, BM=64 -> 256 blocks (in-place on c2)
    up_stage_fused<64><<<R2 / 64, 512, 0, stream>>>(c2, c3, Ws(6), bconv + 6 * HH,
        Ws(7), bconv + 7 * HH, ln_g + 3 * HH, ln_b + 3 * HH, c2, 1024, 512, 10);

    // stage 4 (R1): fused conv1+conv2, BM=64 -> 512 blocks (in-place on c1)
    up_stage_fused<64><<<R1 / 64, 512, 0, stream>>>(c1, c2, Ws(8), bconv + 8 * HH,
        Ws(9), bconv + 9 * HH, ln_g + 4 * HH, ln_b + 4 * HH, c1, 2048, 1024, 11);

    // stage 5 (R0): materialized upsample; BM=128 convs (512 blocks)
    upsample_add_kernel<<<R0 / 8, 256, 0, stream>>>(c0, c1, 2048, 12, R0);
    conv_fused<128, 0, 1, 0, 0><<<R0 / 128, 512, 0, stream>>>(c0, nullptr, nullptr, Ws(10), Wn(10),
        bconv + 10 * HH, nullptr, nullptr, t1, 4096, 0, 0);
    conv_fused<128, 0, 1, 1, 2><<<R0 / 128, 512, 0, stream>>>(t1, nullptr, nullptr, Ws(11), Wn(11),
        bconv + 11 * HH, ln_g + 5 * HH, ln_b + 5 * HH, out, 4096, 0, 0);
}